// Round 1
// baseline (690.368 us; speedup 1.0000x reference)
//
#include <hip/hip_runtime.h>

#define CDIV(a,b) (((a)+(b)-1)/(b))

typedef __attribute__((ext_vector_type(8))) short bf16x8;
typedef __attribute__((ext_vector_type(4))) float f32x4;

__device__ __forceinline__ unsigned short f2b(float v) {
  union { float f; unsigned u; } x; x.f = v;
  unsigned r = x.u + 0x7FFFu + ((x.u >> 16) & 1u);
  return (unsigned short)(r >> 16);
}

__device__ __forceinline__ void gload_lds16(const void* g, void* l) {
  __builtin_amdgcn_global_load_lds(
      (const __attribute__((address_space(1))) unsigned int*)(g),
      (__attribute__((address_space(3))) unsigned int*)(l), 16, 0, 0);
}

// ---------------- MFMA bf16 GEMM: C[M,N] = A[M,K] * Bt[N,K]^T ----------------
// M%128==0, N%128==0, K%64==0. fp32 accumulate/output.
__global__ __launch_bounds__(256) void gemm_bf16_tn(
    const unsigned short* __restrict__ A,
    const unsigned short* __restrict__ Bt,
    float* __restrict__ C,
    int M, int N, int K)
{
  __shared__ __align__(16) unsigned short As[128 * 64];
  __shared__ __align__(16) unsigned short Bs[128 * 64];
  const int tid = threadIdx.x;
  const int lane = tid & 63;
  const int wid = tid >> 6;
  const int wm = (wid >> 1) * 64;
  const int wn = (wid & 1) * 64;
  const long bm = (long)blockIdx.x * 128;
  const long bn = (long)blockIdx.y * 128;

  f32x4 acc[4][4] = {};

  const int lr = tid >> 3;        // 0..31
  const int lc = (tid & 7) * 8;   // elem col offset (16B granules)

  for (int k0 = 0; k0 < K; k0 += 64) {
#pragma unroll
    for (int i = 0; i < 4; ++i) {
      const int row = i * 32 + lr;            // 0..127
      const int eoff = (i * 256 + tid) * 8;   // linear elem in [128][64] tile
      gload_lds16(A  + (bm + row) * (long)K + k0 + lc, As + eoff);
      gload_lds16(Bt + (bn + row) * (long)K + k0 + lc, Bs + eoff);
    }
    __syncthreads();
#pragma unroll
    for (int kk = 0; kk < 2; ++kk) {
      const int ko = kk * 32 + (lane >> 4) * 8;
      const int rsel = lane & 15;
      bf16x8 av[4], bv[4];
#pragma unroll
      for (int m = 0; m < 4; ++m)
        av[m] = *(const bf16x8*)(As + (wm + m * 16 + rsel) * 64 + ko);
#pragma unroll
      for (int n = 0; n < 4; ++n)
        bv[n] = *(const bf16x8*)(Bs + (wn + n * 16 + rsel) * 64 + ko);
#pragma unroll
      for (int m = 0; m < 4; ++m)
#pragma unroll
        for (int n = 0; n < 4; ++n)
          acc[m][n] = __builtin_amdgcn_mfma_f32_16x16x32_bf16(av[m], bv[n], acc[m][n], 0, 0, 0);
    }
    __syncthreads();
  }
  const int crow0 = (lane >> 4) * 4;
  const int ccol = lane & 15;
#pragma unroll
  for (int m = 0; m < 4; ++m)
#pragma unroll
    for (int n = 0; n < 4; ++n) {
      const long r = bm + wm + m * 16 + crow0;
      const long c = bn + wn + n * 16 + ccol;
#pragma unroll
      for (int q = 0; q < 4; ++q)
        C[(r + q) * (long)N + c] = acc[m][n][q];
    }
}

// ---------------- small helpers ----------------
__global__ void zero_i32(int* p, int n) { int i = blockIdx.x*256+threadIdx.x; if (i < n) p[i] = 0; }
__global__ void zero_f32(float* p, int n) { int i = blockIdx.x*256+threadIdx.x; if (i < n) p[i] = 0.f; }
__global__ void fill_ones(float* p, int n) { int i = blockIdx.x*256+threadIdx.x; if (i < n) p[i] = 1.f; }

__global__ void deg_edges(const int* __restrict__ ei, const float* __restrict__ ew,
                          float* __restrict__ deg, int E) {
  int e = blockIdx.x*256+threadIdx.x;
  if (e < E) atomicAdd(&deg[ei[E + e]], ew[e]);
}
__global__ void make_dinv(float* p, int n) {
  int i = blockIdx.x*256+threadIdx.x; if (i < n) p[i] = rsqrtf(p[i]);
}
__global__ void flag_set(const int* __restrict__ idxa, int B_, int* __restrict__ flag) {
  int i = blockIdx.x*256+threadIdx.x; if (i < B_) flag[idxa[i]] = 1;
}
__global__ void flag_slot(int* __restrict__ flag, int n, int* __restrict__ ctr) {
  int i = blockIdx.x*256+threadIdx.x;
  if (i < n && flag[i]) flag[i] = atomicAdd(ctr, 1) + 1;
}
__global__ void init_agg(const float* __restrict__ X, const float* __restrict__ dinv,
                         const int* __restrict__ flag, float* __restrict__ agg, int K) {
  int n = blockIdx.x; int s = flag[n]; if (!s) return;
  float c = dinv[n] * dinv[n];
  const float* xr = X + (long)n * K;
  float* ar = agg + (long)(s - 1) * K;
  for (int i = threadIdx.x; i < K; i += 256) ar[i] = c * xr[i];
}
__global__ void edge_scatter(const int* __restrict__ ei, const float* __restrict__ ew,
                             const float* __restrict__ dinv, const int* __restrict__ flag,
                             const float* __restrict__ X, float* __restrict__ agg,
                             int E, int K) {
  int e = blockIdx.x;
  int dst = ei[E + e];
  int s = flag[dst]; if (!s) return;
  int src = ei[e];
  float coef = ew[e] * dinv[src] * dinv[dst];
  const float* xr = X + (long)src * K;
  float* ar = agg + (long)(s - 1) * K;
  for (int i = threadIdx.x; i < K; i += 256) atomicAdd(&ar[i], coef * xr[i]);
}
__global__ void gatherA(const float* __restrict__ agg, const int* __restrict__ idxa,
                        const int* __restrict__ flag, unsigned short* __restrict__ Ab,
                        int K, int Kp) {
  int idx = blockIdx.x*256+threadIdx.x;
  if (idx >= 2048 * Kp) return;
  int b = idx / Kp, k = idx % Kp;
  float v = 0.f;
  if (k < K) v = agg[(long)(flag[idxa[b]] - 1) * K + k];
  Ab[idx] = f2b(v);
}

// Wt[Np][Kp] = bf16(W[K,N]^T), zero-padded
__global__ void transposeW(const float* __restrict__ W, unsigned short* __restrict__ Wt,
                           int K, int N, int Kp, int Np_) {
  __shared__ float tile[32][33];
  int k0 = blockIdx.x * 32, n0 = blockIdx.y * 32;
  for (int i = threadIdx.y; i < 32; i += 8) {
    int k = k0 + i, n = n0 + threadIdx.x;
    tile[i][threadIdx.x] = (k < K && n < N) ? W[(size_t)k * N + n] : 0.f;
  }
  __syncthreads();
  for (int i = threadIdx.y; i < 32; i += 8) {
    int n = n0 + i, k = k0 + threadIdx.x;
    if (n < Np_ && k < Kp) Wt[(size_t)n * Kp + k] = f2b(tile[threadIdx.x][i]);
  }
}

__global__ void colstats(const float* __restrict__ Z, int ldz, int cols,
                         float* __restrict__ csum, float* __restrict__ csumsq) {
  int col = blockIdx.x * 256 + threadIdx.x;
  if (col >= cols) return;
  int r0 = blockIdx.y * 128;
  float s = 0.f, s2 = 0.f;
  for (int r = r0; r < r0 + 128; ++r) {
    float v = Z[(long)r * ldz + col];
    s += v; s2 += v * v;
  }
  atomicAdd(&csum[col], s);
  atomicAdd(&csumsq[col], s2);
}

__global__ void bn_finalize(const float* __restrict__ csum, const float* __restrict__ csumsq,
                            const float* __restrict__ g, const float* __restrict__ beta,
                            float* __restrict__ scale, float* __restrict__ shift, int cols) {
  int j = blockIdx.x*256+threadIdx.x; if (j >= cols) return;
  const float invB = 1.f / 2048.f;
  float m = csum[j] * invB;
  float v = fmaxf(csumsq[j] * invB - m * m, 0.f);
  float sc = g[j] * rsqrtf(v + 1e-5f);
  scale[j] = sc;
  shift[j] = beta[j] - m * sc;
}

// val = act(Z*scale + shift); scale==null -> scale=1 (GCN bias path)
__global__ void apply_act(const float* __restrict__ Z, int ldz, int total, int cols,
                          const float* __restrict__ scale, const float* __restrict__ shift,
                          int leaky,
                          float* __restrict__ f32out, int ldf,
                          unsigned short* __restrict__ b16out, int ldb) {
  int idx = blockIdx.x*256+threadIdx.x;
  if (idx >= total) return;
  int b = idx / cols, j = idx % cols;
  float v = Z[(long)b * ldz + j];
  v = scale ? v * scale[j] + shift[j] : v + shift[j];
  v = (v >= 0.f) ? v : (leaky ? 0.01f * v : 0.f);
  if (f32out) f32out[(long)b * ldf + j] = v;
  if (b16out) b16out[(long)b * ldb + j] = f2b(v);
}

__global__ void feat_copy(const float* __restrict__ dv, const float* __restrict__ pe,
                          float* __restrict__ f32out, unsigned short* __restrict__ b16out) {
  int idx = blockIdx.x*256+threadIdx.x;
  if (idx >= 2048 * 1324) return;
  int b = idx / 1324, c = idx % 1324;
  float v = (c < 300) ? dv[b * 300 + c] : pe[(long)b * 1024 + (c - 300)];
  f32out[(long)b * 3372 + c] = v;
  b16out[(long)b * 3456 + c] = f2b(v);
}
__global__ void feat_pad(unsigned short* __restrict__ b16out) {
  int idx = blockIdx.x*256+threadIdx.x;
  if (idx >= 2048 * 84) return;
  int b = idx / 84, c = 3372 + idx % 84;
  b16out[(long)b * 3456 + c] = 0;
}

__global__ void gemm_small_f32(const float* __restrict__ A, const float* __restrict__ Bw,
                               float* __restrict__ C, int M, int N, int K) {
  int idx = blockIdx.x*256+threadIdx.x;
  if (idx >= M * N) return;
  int b = idx / N, j = idx % N;
  float s = 0.f;
  for (int k = 0; k < K; ++k) s += A[(long)b * K + k] * Bw[k * N + j];
  C[idx] = s;
}

__global__ void yfinal(const float* __restrict__ h5, const float* __restrict__ W2,
                       const float* __restrict__ b2, float* __restrict__ y) {
  int b = blockIdx.x*256+threadIdx.x;
  if (b >= 2048) return;
  float s = b2[0];
  for (int k = 0; k < 64; ++k) s += h5[b * 64 + k] * W2[k];
  y[b] = s;
}

extern "C" void kernel_launch(void* const* d_in, const int* in_sizes, int n_in,
                              void* d_out, int out_size, void* d_ws, size_t ws_size,
                              hipStream_t stream) {
  (void)in_sizes; (void)n_in; (void)out_size; (void)ws_size;
  const int*   d_index = (const int*)d_in[0];
  const int*   p_index = (const int*)d_in[1];
  const float* d_vecs  = (const float*)d_in[2];
  const float* p_emb   = (const float*)d_in[3];
  const float* d_ecfps = (const float*)d_in[4];
  const int*   d_ei    = (const int*)d_in[5];
  const float* d_ew    = (const float*)d_in[6];
  const float* p_gos   = (const float*)d_in[7];
  const int*   p_ei    = (const int*)d_in[8];
  const float* p_ew    = (const float*)d_in[9];
  const float* d_gcn_W = (const float*)d_in[10];
  const float* d_gcn_b = (const float*)d_in[11];
  const float* p_gcn_W = (const float*)d_in[12];
  const float* p_gcn_b = (const float*)d_in[13];
  const float* enc_W1  = (const float*)d_in[14];
  const float* enc_g1  = (const float*)d_in[16];
  const float* enc_be1 = (const float*)d_in[17];
  const float* enc_W2  = (const float*)d_in[18];
  const float* enc_g2  = (const float*)d_in[20];
  const float* enc_be2 = (const float*)d_in[21];
  const float* dec_W1  = (const float*)d_in[22];
  const float* dec_g1  = (const float*)d_in[24];
  const float* dec_be1 = (const float*)d_in[25];
  const float* dec_W2  = (const float*)d_in[26];
  const float* dec_g2  = (const float*)d_in[28];
  const float* dec_be2 = (const float*)d_in[29];
  const float* out_W1  = (const float*)d_in[30];
  const float* out_g1  = (const float*)d_in[32];
  const float* out_be1 = (const float*)d_in[33];
  const float* out_W2  = (const float*)d_in[34];
  const float* out_b2  = (const float*)d_in[35];

  float* out = (float*)d_out;
  float* y_out    = out;                                    // [2048]
  float* enc_out  = out + 2048;                             // [2048,256]
  float* dec_out  = out + 526336;                           // [2048,3372]
  float* feat_out = out + 7432192;                          // [2048,3372]

  char* ws = (char*)d_ws;
  size_t off = 0;
  auto alloc = [&](size_t bytes) {
    size_t o = off; off = (off + bytes + 255) & ~(size_t)255; return (void*)(ws + o);
  };
  int* flag_d = (int*)alloc((size_t)15002 * 4);
  int* flag_p = flag_d + 10000;
  int* ctr    = flag_d + 15000;
  float* deg   = (float*)alloc((size_t)15000 * 4);
  float* deg_d = deg;
  float* deg_p = deg + 10000;
  float* aggd = (float*)alloc((size_t)2048 * 1024 * 4);
  float* aggp = (float*)alloc((size_t)2048 * 2812 * 4);
  unsigned short* Adb   = (unsigned short*)alloc((size_t)2048 * 1024 * 2);
  unsigned short* Apb   = (unsigned short*)alloc((size_t)2048 * 2816 * 2);
  unsigned short* WdT   = (unsigned short*)alloc((size_t)1024 * 1024 * 2);
  unsigned short* WpT   = (unsigned short*)alloc((size_t)1024 * 2816 * 2);
  unsigned short* eW1T  = (unsigned short*)alloc((size_t)1024 * 3456 * 2);
  unsigned short* eW2T  = (unsigned short*)alloc((size_t)256 * 1024 * 2);
  unsigned short* dW1T  = (unsigned short*)alloc((size_t)1024 * 256 * 2);
  unsigned short* dW2T  = (unsigned short*)alloc((size_t)3456 * 1024 * 2);
  unsigned short* featb = (unsigned short*)alloc((size_t)2048 * 3456 * 2);
  float* Z    = (float*)alloc((size_t)2048 * 3456 * 4);
  unsigned short* h1b  = (unsigned short*)alloc((size_t)2048 * 1024 * 2);
  unsigned short* encb = (unsigned short*)alloc((size_t)2048 * 256 * 2);
  unsigned short* h3b  = (unsigned short*)alloc((size_t)2048 * 1024 * 2);
  float* h5   = (float*)alloc((size_t)2048 * 64 * 4);
  float* csum = (float*)alloc((size_t)2 * 3456 * 4);
  float* csumsq = csum + 3456;
  float* bscale = (float*)alloc((size_t)2 * 3456 * 4);
  float* bshift = bscale + 3456;

  // ---- GCN prep: degrees, needed-node flags/slots, aggregate X ----
  zero_i32<<<CDIV(15002,256),256,0,stream>>>(flag_d, 15002);
  fill_ones<<<CDIV(15000,256),256,0,stream>>>(deg, 15000);
  deg_edges<<<CDIV(65536,256),256,0,stream>>>(d_ei, d_ew, deg_d, 65536);
  deg_edges<<<CDIV(25000,256),256,0,stream>>>(p_ei, p_ew, deg_p, 25000);
  make_dinv<<<CDIV(15000,256),256,0,stream>>>(deg, 15000);
  flag_set<<<8,256,0,stream>>>(d_index, 2048, flag_d);
  flag_set<<<8,256,0,stream>>>(p_index, 2048, flag_p);
  flag_slot<<<CDIV(10000,256),256,0,stream>>>(flag_d, 10000, ctr);
  flag_slot<<<CDIV(5000,256),256,0,stream>>>(flag_p, 5000, ctr + 1);
  init_agg<<<10000,256,0,stream>>>(d_ecfps, deg_d, flag_d, aggd, 1024);
  init_agg<<<5000,256,0,stream>>>(p_gos, deg_p, flag_p, aggp, 2812);
  edge_scatter<<<65536,256,0,stream>>>(d_ei, d_ew, deg_d, flag_d, d_ecfps, aggd, 65536, 1024);
  edge_scatter<<<25000,256,0,stream>>>(p_ei, p_ew, deg_p, flag_p, p_gos, aggp, 25000, 2812);
  gatherA<<<CDIV(2048*1024,256),256,0,stream>>>(aggd, d_index, flag_d, Adb, 1024, 1024);
  gatherA<<<CDIV(2048*2816,256),256,0,stream>>>(aggp, p_index, flag_p, Apb, 2812, 2816);

  // ---- weight transposes to bf16 [N,K] (padded) ----
  dim3 tb(32, 8);
  transposeW<<<dim3(32, 32), tb, 0, stream>>>(d_gcn_W, WdT, 1024, 1024, 1024, 1024);
  transposeW<<<dim3(88, 32), tb, 0, stream>>>(p_gcn_W, WpT, 2812, 1024, 2816, 1024);
  transposeW<<<dim3(108, 32), tb, 0, stream>>>(enc_W1, eW1T, 3372, 1024, 3456, 1024);
  transposeW<<<dim3(32, 8),  tb, 0, stream>>>(enc_W2, eW2T, 1024, 256, 1024, 256);
  transposeW<<<dim3(8, 32),  tb, 0, stream>>>(dec_W1, dW1T, 256, 1024, 256, 1024);
  transposeW<<<dim3(32, 108),tb, 0, stream>>>(dec_W2, dW2T, 1024, 3372, 1024, 3456);

  // ---- GCN GEMMs -> feature ----
  gemm_bf16_tn<<<dim3(16,8),256,0,stream>>>(Adb, WdT, Z, 2048, 1024, 1024);
  apply_act<<<CDIV(2048*1024,256),256,0,stream>>>(Z, 1024, 2048*1024, 1024,
      nullptr, d_gcn_b, 1, feat_out + 1324, 3372, featb + 1324, 3456);
  gemm_bf16_tn<<<dim3(16,8),256,0,stream>>>(Apb, WpT, Z, 2048, 1024, 2816);
  apply_act<<<CDIV(2048*1024,256),256,0,stream>>>(Z, 1024, 2048*1024, 1024,
      nullptr, p_gcn_b, 1, feat_out + 2348, 3372, featb + 2348, 3456);
  feat_copy<<<CDIV(2048*1324,256),256,0,stream>>>(d_vecs, p_emb, feat_out, featb);
  feat_pad<<<CDIV(2048*84,256),256,0,stream>>>(featb);

  // ---- encoder L1: [2048,3456] x [3456,1024] ----
  gemm_bf16_tn<<<dim3(16,8),256,0,stream>>>(featb, eW1T, Z, 2048, 1024, 3456);
  zero_f32<<<CDIV(2*3456,256),256,0,stream>>>(csum, 2*3456);
  colstats<<<dim3(4,16),256,0,stream>>>(Z, 1024, 1024, csum, csumsq);
  bn_finalize<<<4,256,0,stream>>>(csum, csumsq, enc_g1, enc_be1, bscale, bshift, 1024);
  apply_act<<<CDIV(2048*1024,256),256,0,stream>>>(Z, 1024, 2048*1024, 1024,
      bscale, bshift, 0, nullptr, 0, h1b, 1024);

  // ---- encoder L2: [2048,1024] x [1024,256] -> encoded ----
  gemm_bf16_tn<<<dim3(16,2),256,0,stream>>>(h1b, eW2T, Z, 2048, 256, 1024);
  zero_f32<<<CDIV(2*3456,256),256,0,stream>>>(csum, 2*3456);
  colstats<<<dim3(1,16),256,0,stream>>>(Z, 256, 256, csum, csumsq);
  bn_finalize<<<1,256,0,stream>>>(csum, csumsq, enc_g2, enc_be2, bscale, bshift, 256);
  apply_act<<<CDIV(2048*256,256),256,0,stream>>>(Z, 256, 2048*256, 256,
      bscale, bshift, 0, enc_out, 256, encb, 256);

  // ---- decoder L1: [2048,256] x [256,1024] ----
  gemm_bf16_tn<<<dim3(16,8),256,0,stream>>>(encb, dW1T, Z, 2048, 1024, 256);
  zero_f32<<<CDIV(2*3456,256),256,0,stream>>>(csum, 2*3456);
  colstats<<<dim3(4,16),256,0,stream>>>(Z, 1024, 1024, csum, csumsq);
  bn_finalize<<<4,256,0,stream>>>(csum, csumsq, dec_g1, dec_be1, bscale, bshift, 1024);
  apply_act<<<CDIV(2048*1024,256),256,0,stream>>>(Z, 1024, 2048*1024, 1024,
      bscale, bshift, 0, nullptr, 0, h3b, 1024);

  // ---- decoder L2: [2048,1024] x [1024,3456] -> decoded ----
  gemm_bf16_tn<<<dim3(16,27),256,0,stream>>>(h3b, dW2T, Z, 2048, 3456, 1024);
  zero_f32<<<CDIV(2*3456,256),256,0,stream>>>(csum, 2*3456);
  colstats<<<dim3(14,16),256,0,stream>>>(Z, 3456, 3372, csum, csumsq);
  bn_finalize<<<14,256,0,stream>>>(csum, csumsq, dec_g2, dec_be2, bscale, bshift, 3372);
  apply_act<<<CDIV(2048*3372,256),256,0,stream>>>(Z, 3456, 2048*3372, 3372,
      bscale, bshift, 0, dec_out, 3372, nullptr, 0);

  // ---- head: [2048,256] x [256,64] -> lrelu(bn) -> [2048,64] x [64,1] ----
  gemm_small_f32<<<CDIV(2048*64,256),256,0,stream>>>(enc_out, out_W1, Z, 2048, 64, 256);
  zero_f32<<<CDIV(2*3456,256),256,0,stream>>>(csum, 2*3456);
  colstats<<<dim3(1,16),256,0,stream>>>(Z, 64, 64, csum, csumsq);
  bn_finalize<<<1,256,0,stream>>>(csum, csumsq, out_g1, out_be1, bscale, bshift, 64);
  apply_act<<<CDIV(2048*64,256),256,0,stream>>>(Z, 64, 2048*64, 64,
      bscale, bshift, 1, h5, 64, nullptr, 0);
  yfinal<<<8,256,0,stream>>>(h5, out_W2, out_b2, y_out);
}

// Round 2
// 584.986 us; speedup vs baseline: 1.1801x; 1.1801x over previous
//
#include <hip/hip_runtime.h>

#define CDIV(a,b) (((a)+(b)-1)/(b))

typedef __attribute__((ext_vector_type(8))) short bf16x8;
typedef __attribute__((ext_vector_type(4))) float f32x4;

__device__ __forceinline__ unsigned short f2b(float v) {
  union { float f; unsigned u; } x; x.f = v;
  unsigned r = x.u + 0x7FFFu + ((x.u >> 16) & 1u);
  return (unsigned short)(r >> 16);
}

__device__ __forceinline__ void gload_lds16(const void* g, void* l) {
  __builtin_amdgcn_global_load_lds(
      (const __attribute__((address_space(1))) unsigned int*)(g),
      (__attribute__((address_space(3))) unsigned int*)(l), 16, 0, 0);
}

// ---------------- MFMA bf16 GEMM 128x128: C[M,N] = A[M,K] * Bt[N,K]^T -------
__global__ __launch_bounds__(256) void gemm_bf16_tn(
    const unsigned short* __restrict__ A,
    const unsigned short* __restrict__ Bt,
    float* __restrict__ C,
    int M, int N, int K)
{
  __shared__ __align__(16) unsigned short As[128 * 64];
  __shared__ __align__(16) unsigned short Bs[128 * 64];
  const int tid = threadIdx.x;
  const int lane = tid & 63;
  const int wid = tid >> 6;
  const int wm = (wid >> 1) * 64;
  const int wn = (wid & 1) * 64;
  const long bm = (long)blockIdx.x * 128;
  const long bn = (long)blockIdx.y * 128;

  f32x4 acc[4][4] = {};

  const int lr = tid >> 3;
  const int lc = (tid & 7) * 8;

  for (int k0 = 0; k0 < K; k0 += 64) {
#pragma unroll
    for (int i = 0; i < 4; ++i) {
      const int row = i * 32 + lr;
      const int eoff = (i * 256 + tid) * 8;
      gload_lds16(A  + (bm + row) * (long)K + k0 + lc, As + eoff);
      gload_lds16(Bt + (bn + row) * (long)K + k0 + lc, Bs + eoff);
    }
    __syncthreads();
#pragma unroll
    for (int kk = 0; kk < 2; ++kk) {
      const int ko = kk * 32 + (lane >> 4) * 8;
      const int rsel = lane & 15;
      bf16x8 av[4], bv[4];
#pragma unroll
      for (int m = 0; m < 4; ++m)
        av[m] = *(const bf16x8*)(As + (wm + m * 16 + rsel) * 64 + ko);
#pragma unroll
      for (int n = 0; n < 4; ++n)
        bv[n] = *(const bf16x8*)(Bs + (wn + n * 16 + rsel) * 64 + ko);
#pragma unroll
      for (int m = 0; m < 4; ++m)
#pragma unroll
        for (int n = 0; n < 4; ++n)
          acc[m][n] = __builtin_amdgcn_mfma_f32_16x16x32_bf16(av[m], bv[n], acc[m][n], 0, 0, 0);
    }
    __syncthreads();
  }
  const int crow0 = (lane >> 4) * 4;
  const int ccol = lane & 15;
#pragma unroll
  for (int m = 0; m < 4; ++m)
#pragma unroll
    for (int n = 0; n < 4; ++n) {
      const long r = bm + wm + m * 16 + crow0;
      const long c = bn + wn + n * 16 + ccol;
#pragma unroll
      for (int q = 0; q < 4; ++q)
        C[(r + q) * (long)N + c] = acc[m][n][q];
    }
}

// ---------------- MFMA bf16 GEMM 64x128 (better occupancy for small grids) --
__global__ __launch_bounds__(256) void gemm64_bf16_tn(
    const unsigned short* __restrict__ A,
    const unsigned short* __restrict__ Bt,
    float* __restrict__ C,
    int M, int N, int K)
{
  __shared__ __align__(16) unsigned short As[64 * 64];
  __shared__ __align__(16) unsigned short Bs[128 * 64];
  const int tid = threadIdx.x;
  const int lane = tid & 63;
  const int wid = tid >> 6;
  const int wn = wid * 32;
  const long bm = (long)blockIdx.x * 64;
  const long bn = (long)blockIdx.y * 128;

  f32x4 acc[4][2] = {};

  const int lr = tid >> 3;
  const int lc = (tid & 7) * 8;

  for (int k0 = 0; k0 < K; k0 += 64) {
#pragma unroll
    for (int i = 0; i < 2; ++i) {
      const int row = i * 32 + lr;
      const int eoff = (i * 256 + tid) * 8;
      gload_lds16(A + (bm + row) * (long)K + k0 + lc, As + eoff);
    }
#pragma unroll
    for (int i = 0; i < 4; ++i) {
      const int row = i * 32 + lr;
      const int eoff = (i * 256 + tid) * 8;
      gload_lds16(Bt + (bn + row) * (long)K + k0 + lc, Bs + eoff);
    }
    __syncthreads();
#pragma unroll
    for (int kk = 0; kk < 2; ++kk) {
      const int ko = kk * 32 + (lane >> 4) * 8;
      const int rsel = lane & 15;
      bf16x8 av[4], bv[2];
#pragma unroll
      for (int m = 0; m < 4; ++m)
        av[m] = *(const bf16x8*)(As + (m * 16 + rsel) * 64 + ko);
#pragma unroll
      for (int n = 0; n < 2; ++n)
        bv[n] = *(const bf16x8*)(Bs + (wn + n * 16 + rsel) * 64 + ko);
#pragma unroll
      for (int m = 0; m < 4; ++m)
#pragma unroll
        for (int n = 0; n < 2; ++n)
          acc[m][n] = __builtin_amdgcn_mfma_f32_16x16x32_bf16(av[m], bv[n], acc[m][n], 0, 0, 0);
    }
    __syncthreads();
  }
  const int crow0 = (lane >> 4) * 4;
  const int ccol = lane & 15;
#pragma unroll
  for (int m = 0; m < 4; ++m)
#pragma unroll
    for (int n = 0; n < 2; ++n) {
      const long r = bm + m * 16 + crow0;
      const long c = bn + wn + n * 16 + ccol;
#pragma unroll
      for (int q = 0; q < 4; ++q)
        C[(r + q) * (long)N + c] = acc[m][n][q];
    }
}

// ---------------- small helpers ----------------
__global__ void zero_i32(int* p, int n) { int i = blockIdx.x*256+threadIdx.x; if (i < n) p[i] = 0; }
__global__ void zero_f32(float* p, int n) { int i = blockIdx.x*256+threadIdx.x; if (i < n) p[i] = 0.f; }
__global__ void fill_ones(float* p, int n) { int i = blockIdx.x*256+threadIdx.x; if (i < n) p[i] = 1.f; }

__global__ void deg_edges(const int* __restrict__ ei, const float* __restrict__ ew,
                          float* __restrict__ deg, int E) {
  int e = blockIdx.x*256+threadIdx.x;
  if (e < E) atomicAdd(&deg[ei[E + e]], ew[e]);
}
__global__ void make_dinv(float* p, int n) {
  int i = blockIdx.x*256+threadIdx.x; if (i < n) p[i] = rsqrtf(p[i]);
}
__global__ void flag_set(const int* __restrict__ idxa, int B_, int* __restrict__ flag) {
  int i = blockIdx.x*256+threadIdx.x; if (i < B_) flag[idxa[i]] = 1;
}
__global__ void flag_slot(int* __restrict__ flag, int n, int* __restrict__ ctr,
                          int* __restrict__ slotnode) {
  int i = blockIdx.x*256+threadIdx.x;
  if (i < n && flag[i]) {
    int s = atomicAdd(ctr, 1);
    flag[i] = s + 1;
    slotnode[s] = i;
  }
}
__global__ void hist_edges(const int* __restrict__ ei, const int* __restrict__ flag,
                           int* __restrict__ cnt, int E) {
  int e = blockIdx.x*256+threadIdx.x; if (e >= E) return;
  int s = flag[ei[E + e]];
  if (s) atomicAdd(&cnt[s - 1], 1);
}
// exclusive scan of cnt[0..2047] -> rowptr[0..2048], single block of 256
__global__ void scan2048(const int* __restrict__ cnt, int* __restrict__ rowptr) {
  __shared__ int part[256];
  int tid = threadIdx.x;
  int base = tid * 8;
  int vals[8]; int s = 0;
#pragma unroll
  for (int i = 0; i < 8; ++i) { vals[i] = s; s += cnt[base + i]; }
  part[tid] = s;
  __syncthreads();
  if (tid == 0) { int r = 0; for (int i = 0; i < 256; ++i) { int t = part[i]; part[i] = r; r += t; } }
  __syncthreads();
  int off = part[tid];
#pragma unroll
  for (int i = 0; i < 8; ++i) rowptr[base + i] = off + vals[i];
  if (tid == 255) rowptr[2048] = off + s;
}
__global__ void fill_edges(const int* __restrict__ ei, const float* __restrict__ ew,
                           const float* __restrict__ dinv, const int* __restrict__ flag,
                           const int* __restrict__ rowptr, int* __restrict__ fillp,
                           int* __restrict__ esrc, float* __restrict__ ecoef, int E) {
  int e = blockIdx.x*256+threadIdx.x; if (e >= E) return;
  int dst = ei[E + e];
  int s = flag[dst]; if (!s) return;
  int src = ei[e];
  int pos = rowptr[s - 1] + atomicAdd(&fillp[s - 1], 1);
  esrc[pos] = src;
  ecoef[pos] = ew[e] * dinv[src] * dinv[dst];
}
// per flagged dst: agg_b[slot] = bf16( dinv^2*X[node] + sum_e coef*X[src] )
__global__ void gather_agg(const float* __restrict__ X, const float* __restrict__ dinv,
                           const int* __restrict__ slotnode, const int* __restrict__ rowptr,
                           const int* __restrict__ esrc, const float* __restrict__ ecoef,
                           const int* __restrict__ nflag,
                           unsigned short* __restrict__ aggb, int K) {
  int s = blockIdx.x; if (s >= *nflag) return;
  int n = slotnode[s];
  float dn = dinv[n];
  float selfc = dn * dn;
  int e0 = rowptr[s], e1 = rowptr[s + 1];
  const float* xn = X + (long)n * K;
  unsigned short* ar = aggb + (long)s * K;
  for (int col = threadIdx.x; col < K; col += 256) {
    float acc = selfc * xn[col];
    for (int e = e0; e < e1; ++e)
      acc += ecoef[e] * X[(long)esrc[e] * K + col];
    ar[col] = f2b(acc);
  }
}
__global__ void gatherA(const unsigned short* __restrict__ aggb, const int* __restrict__ idxa,
                        const int* __restrict__ flag, unsigned short* __restrict__ Ab,
                        int K, int Kp) {
  int idx = blockIdx.x*256+threadIdx.x;
  if (idx >= 2048 * Kp) return;
  int b = idx / Kp, k = idx % Kp;
  Ab[idx] = (k < K) ? aggb[(long)(flag[idxa[b]] - 1) * K + k] : (unsigned short)0;
}

// Wt[Np][Kp] = bf16(W[K,N]^T), zero-padded
__global__ void transposeW(const float* __restrict__ W, unsigned short* __restrict__ Wt,
                           int K, int N, int Kp, int Np_) {
  __shared__ float tile[32][33];
  int k0 = blockIdx.x * 32, n0 = blockIdx.y * 32;
  for (int i = threadIdx.y; i < 32; i += 8) {
    int k = k0 + i, n = n0 + threadIdx.x;
    tile[i][threadIdx.x] = (k < K && n < N) ? W[(size_t)k * N + n] : 0.f;
  }
  __syncthreads();
  for (int i = threadIdx.y; i < 32; i += 8) {
    int n = n0 + i, k = k0 + threadIdx.x;
    if (n < Np_ && k < Kp) Wt[(size_t)n * Kp + k] = f2b(tile[threadIdx.x][i]);
  }
}

__global__ void colstats(const float* __restrict__ Z, int ldz, int cols,
                         float* __restrict__ csum, float* __restrict__ csumsq) {
  int col = blockIdx.x * 256 + threadIdx.x;
  if (col >= cols) return;
  int r0 = blockIdx.y * 128;
  float s = 0.f, s2 = 0.f;
  for (int r = r0; r < r0 + 128; ++r) {
    float v = Z[(long)r * ldz + col];
    s += v; s2 += v * v;
  }
  atomicAdd(&csum[col], s);
  atomicAdd(&csumsq[col], s2);
}

__global__ void bn_finalize(const float* __restrict__ csum, const float* __restrict__ csumsq,
                            const float* __restrict__ g, const float* __restrict__ beta,
                            float* __restrict__ scale, float* __restrict__ shift, int cols) {
  int j = blockIdx.x*256+threadIdx.x; if (j >= cols) return;
  const float invB = 1.f / 2048.f;
  float m = csum[j] * invB;
  float v = fmaxf(csumsq[j] * invB - m * m, 0.f);
  float sc = g[j] * rsqrtf(v + 1e-5f);
  scale[j] = sc;
  shift[j] = beta[j] - m * sc;
}

__global__ void apply_act(const float* __restrict__ Z, int ldz, int total, int cols,
                          const float* __restrict__ scale, const float* __restrict__ shift,
                          int leaky,
                          float* __restrict__ f32out, int ldf,
                          unsigned short* __restrict__ b16out, int ldb) {
  int idx = blockIdx.x*256+threadIdx.x;
  if (idx >= total) return;
  int b = idx / cols, j = idx % cols;
  float v = Z[(long)b * ldz + j];
  v = scale ? v * scale[j] + shift[j] : v + shift[j];
  v = (v >= 0.f) ? v : (leaky ? 0.01f * v : 0.f);
  if (f32out) f32out[(long)b * ldf + j] = v;
  if (b16out) b16out[(long)b * ldb + j] = f2b(v);
}

__global__ void feat_copy(const float* __restrict__ dv, const float* __restrict__ pe,
                          float* __restrict__ f32out, unsigned short* __restrict__ b16out) {
  int idx = blockIdx.x*256+threadIdx.x;
  if (idx >= 2048 * 1324) return;
  int b = idx / 1324, c = idx % 1324;
  float v = (c < 300) ? dv[b * 300 + c] : pe[(long)b * 1024 + (c - 300)];
  f32out[(long)b * 3372 + c] = v;
  b16out[(long)b * 3456 + c] = f2b(v);
}
__global__ void feat_pad(unsigned short* __restrict__ b16out) {
  int idx = blockIdx.x*256+threadIdx.x;
  if (idx >= 2048 * 84) return;
  int b = idx / 84, c = 3372 + idx % 84;
  b16out[(long)b * 3456 + c] = 0;
}

__global__ void gemm_small_f32(const float* __restrict__ A, const float* __restrict__ Bw,
                               float* __restrict__ C, int M, int N, int K) {
  int idx = blockIdx.x*256+threadIdx.x;
  if (idx >= M * N) return;
  int b = idx / N, j = idx % N;
  float s = 0.f;
  for (int k = 0; k < K; ++k) s += A[(long)b * K + k] * Bw[k * N + j];
  C[idx] = s;
}

__global__ void yfinal(const float* __restrict__ h5, const float* __restrict__ W2,
                       const float* __restrict__ b2, float* __restrict__ y) {
  int b = blockIdx.x*256+threadIdx.x;
  if (b >= 2048) return;
  float s = b2[0];
  for (int k = 0; k < 64; ++k) s += h5[b * 64 + k] * W2[k];
  y[b] = s;
}

extern "C" void kernel_launch(void* const* d_in, const int* in_sizes, int n_in,
                              void* d_out, int out_size, void* d_ws, size_t ws_size,
                              hipStream_t stream) {
  (void)in_sizes; (void)n_in; (void)out_size; (void)ws_size;
  const int*   d_index = (const int*)d_in[0];
  const int*   p_index = (const int*)d_in[1];
  const float* d_vecs  = (const float*)d_in[2];
  const float* p_emb   = (const float*)d_in[3];
  const float* d_ecfps = (const float*)d_in[4];
  const int*   d_ei    = (const int*)d_in[5];
  const float* d_ew    = (const float*)d_in[6];
  const float* p_gos   = (const float*)d_in[7];
  const int*   p_ei    = (const int*)d_in[8];
  const float* p_ew    = (const float*)d_in[9];
  const float* d_gcn_W = (const float*)d_in[10];
  const float* d_gcn_b = (const float*)d_in[11];
  const float* p_gcn_W = (const float*)d_in[12];
  const float* p_gcn_b = (const float*)d_in[13];
  const float* enc_W1  = (const float*)d_in[14];
  const float* enc_g1  = (const float*)d_in[16];
  const float* enc_be1 = (const float*)d_in[17];
  const float* enc_W2  = (const float*)d_in[18];
  const float* enc_g2  = (const float*)d_in[20];
  const float* enc_be2 = (const float*)d_in[21];
  const float* dec_W1  = (const float*)d_in[22];
  const float* dec_g1  = (const float*)d_in[24];
  const float* dec_be1 = (const float*)d_in[25];
  const float* dec_W2  = (const float*)d_in[26];
  const float* dec_g2  = (const float*)d_in[28];
  const float* dec_be2 = (const float*)d_in[29];
  const float* out_W1  = (const float*)d_in[30];
  const float* out_g1  = (const float*)d_in[32];
  const float* out_be1 = (const float*)d_in[33];
  const float* out_W2  = (const float*)d_in[34];
  const float* out_b2  = (const float*)d_in[35];

  float* out = (float*)d_out;
  float* y_out    = out;
  float* enc_out  = out + 2048;
  float* dec_out  = out + 526336;
  float* feat_out = out + 7432192;

  char* ws = (char*)d_ws;
  size_t off = 0;
  auto alloc = [&](size_t bytes) {
    size_t o = off; off = (off + bytes + 255) & ~(size_t)255; return (void*)(ws + o);
  };
  // one contiguous zero-init int region
  int* iz = (int*)alloc((size_t)23194 * 4);
  int* flag_d = iz;              // 10000
  int* flag_p = iz + 10000;      // 5000
  int* cnt_d  = iz + 15000;      // 2048
  int* cnt_p  = iz + 17048;      // 2048
  int* fill_d = iz + 19096;      // 2048
  int* fill_p = iz + 21144;      // 2048
  int* ctr    = iz + 23192;      // 2
  int* slotnode_d = (int*)alloc(2048 * 4);
  int* slotnode_p = (int*)alloc(2048 * 4);
  int* rowptr_d = (int*)alloc(2049 * 4);
  int* rowptr_p = (int*)alloc(2049 * 4);
  int* esrc_d  = (int*)alloc((size_t)65536 * 4);
  float* ecoef_d = (float*)alloc((size_t)65536 * 4);
  int* esrc_p  = (int*)alloc((size_t)25000 * 4);
  float* ecoef_p = (float*)alloc((size_t)25000 * 4);
  float* deg   = (float*)alloc((size_t)15000 * 4);
  float* deg_d = deg;
  float* deg_p = deg + 10000;
  unsigned short* aggd_b = (unsigned short*)alloc((size_t)2048 * 1024 * 2);
  unsigned short* aggp_b = (unsigned short*)alloc((size_t)2048 * 2812 * 2);
  unsigned short* Adb   = (unsigned short*)alloc((size_t)2048 * 1024 * 2);
  unsigned short* Apb   = (unsigned short*)alloc((size_t)2048 * 2816 * 2);
  unsigned short* WdT   = (unsigned short*)alloc((size_t)1024 * 1024 * 2);
  unsigned short* WpT   = (unsigned short*)alloc((size_t)1024 * 2816 * 2);
  unsigned short* eW1T  = (unsigned short*)alloc((size_t)1024 * 3456 * 2);
  unsigned short* eW2T  = (unsigned short*)alloc((size_t)256 * 1024 * 2);
  unsigned short* dW1T  = (unsigned short*)alloc((size_t)1024 * 256 * 2);
  unsigned short* dW2T  = (unsigned short*)alloc((size_t)3456 * 1024 * 2);
  unsigned short* featb = (unsigned short*)alloc((size_t)2048 * 3456 * 2);
  float* Z    = (float*)alloc((size_t)2048 * 3456 * 4);
  unsigned short* h1b  = (unsigned short*)alloc((size_t)2048 * 1024 * 2);
  unsigned short* encb = (unsigned short*)alloc((size_t)2048 * 256 * 2);
  unsigned short* h3b  = (unsigned short*)alloc((size_t)2048 * 1024 * 2);
  float* h5   = (float*)alloc((size_t)2048 * 64 * 4);
  float* csum = (float*)alloc((size_t)2 * 3456 * 4);
  float* csumsq = csum + 3456;
  float* bscale = (float*)alloc((size_t)2 * 3456 * 4);
  float* bshift = bscale + 3456;

  // ---- GCN prep: degrees, flags/slots, CSR by dst, gather-aggregate ----
  zero_i32<<<CDIV(23194,256),256,0,stream>>>(iz, 23194);
  fill_ones<<<CDIV(15000,256),256,0,stream>>>(deg, 15000);
  deg_edges<<<CDIV(65536,256),256,0,stream>>>(d_ei, d_ew, deg_d, 65536);
  deg_edges<<<CDIV(25000,256),256,0,stream>>>(p_ei, p_ew, deg_p, 25000);
  make_dinv<<<CDIV(15000,256),256,0,stream>>>(deg, 15000);
  flag_set<<<8,256,0,stream>>>(d_index, 2048, flag_d);
  flag_set<<<8,256,0,stream>>>(p_index, 2048, flag_p);
  flag_slot<<<CDIV(10000,256),256,0,stream>>>(flag_d, 10000, ctr, slotnode_d);
  flag_slot<<<CDIV(5000,256),256,0,stream>>>(flag_p, 5000, ctr + 1, slotnode_p);
  hist_edges<<<CDIV(65536,256),256,0,stream>>>(d_ei, flag_d, cnt_d, 65536);
  hist_edges<<<CDIV(25000,256),256,0,stream>>>(p_ei, flag_p, cnt_p, 25000);
  scan2048<<<1,256,0,stream>>>(cnt_d, rowptr_d);
  scan2048<<<1,256,0,stream>>>(cnt_p, rowptr_p);
  fill_edges<<<CDIV(65536,256),256,0,stream>>>(d_ei, d_ew, deg_d, flag_d, rowptr_d, fill_d,
                                               esrc_d, ecoef_d, 65536);
  fill_edges<<<CDIV(25000,256),256,0,stream>>>(p_ei, p_ew, deg_p, flag_p, rowptr_p, fill_p,
                                               esrc_p, ecoef_p, 25000);
  gather_agg<<<2048,256,0,stream>>>(d_ecfps, deg_d, slotnode_d, rowptr_d, esrc_d, ecoef_d,
                                    ctr, aggd_b, 1024);
  gather_agg<<<2048,256,0,stream>>>(p_gos, deg_p, slotnode_p, rowptr_p, esrc_p, ecoef_p,
                                    ctr + 1, aggp_b, 2812);
  gatherA<<<CDIV(2048*1024,256),256,0,stream>>>(aggd_b, d_index, flag_d, Adb, 1024, 1024);
  gatherA<<<CDIV(2048*2816,256),256,0,stream>>>(aggp_b, p_index, flag_p, Apb, 2812, 2816);

  // ---- weight transposes to bf16 [N,K] (padded) ----
  dim3 tb(32, 8);
  transposeW<<<dim3(32, 32), tb, 0, stream>>>(d_gcn_W, WdT, 1024, 1024, 1024, 1024);
  transposeW<<<dim3(88, 32), tb, 0, stream>>>(p_gcn_W, WpT, 2812, 1024, 2816, 1024);
  transposeW<<<dim3(108, 32), tb, 0, stream>>>(enc_W1, eW1T, 3372, 1024, 3456, 1024);
  transposeW<<<dim3(32, 8),  tb, 0, stream>>>(enc_W2, eW2T, 1024, 256, 1024, 256);
  transposeW<<<dim3(8, 32),  tb, 0, stream>>>(dec_W1, dW1T, 256, 1024, 256, 1024);
  transposeW<<<dim3(32, 108),tb, 0, stream>>>(dec_W2, dW2T, 1024, 3372, 1024, 3456);

  // ---- GCN GEMMs -> feature ----
  gemm64_bf16_tn<<<dim3(32,8),256,0,stream>>>(Adb, WdT, Z, 2048, 1024, 1024);
  apply_act<<<CDIV(2048*1024,256),256,0,stream>>>(Z, 1024, 2048*1024, 1024,
      nullptr, d_gcn_b, 1, feat_out + 1324, 3372, featb + 1324, 3456);
  gemm64_bf16_tn<<<dim3(32,8),256,0,stream>>>(Apb, WpT, Z, 2048, 1024, 2816);
  apply_act<<<CDIV(2048*1024,256),256,0,stream>>>(Z, 1024, 2048*1024, 1024,
      nullptr, p_gcn_b, 1, feat_out + 2348, 3372, featb + 2348, 3456);
  feat_copy<<<CDIV(2048*1324,256),256,0,stream>>>(d_vecs, p_emb, feat_out, featb);
  feat_pad<<<CDIV(2048*84,256),256,0,stream>>>(featb);

  // ---- encoder L1 ----
  gemm64_bf16_tn<<<dim3(32,8),256,0,stream>>>(featb, eW1T, Z, 2048, 1024, 3456);
  zero_f32<<<CDIV(2*3456,256),256,0,stream>>>(csum, 2*3456);
  colstats<<<dim3(4,16),256,0,stream>>>(Z, 1024, 1024, csum, csumsq);
  bn_finalize<<<4,256,0,stream>>>(csum, csumsq, enc_g1, enc_be1, bscale, bshift, 1024);
  apply_act<<<CDIV(2048*1024,256),256,0,stream>>>(Z, 1024, 2048*1024, 1024,
      bscale, bshift, 0, nullptr, 0, h1b, 1024);

  // ---- encoder L2 -> encoded ----
  gemm64_bf16_tn<<<dim3(32,2),256,0,stream>>>(h1b, eW2T, Z, 2048, 256, 1024);
  zero_f32<<<CDIV(2*3456,256),256,0,stream>>>(csum, 2*3456);
  colstats<<<dim3(1,16),256,0,stream>>>(Z, 256, 256, csum, csumsq);
  bn_finalize<<<1,256,0,stream>>>(csum, csumsq, enc_g2, enc_be2, bscale, bshift, 256);
  apply_act<<<CDIV(2048*256,256),256,0,stream>>>(Z, 256, 2048*256, 256,
      bscale, bshift, 0, enc_out, 256, encb, 256);

  // ---- decoder L1 ----
  gemm64_bf16_tn<<<dim3(32,8),256,0,stream>>>(encb, dW1T, Z, 2048, 1024, 256);
  zero_f32<<<CDIV(2*3456,256),256,0,stream>>>(csum, 2*3456);
  colstats<<<dim3(4,16),256,0,stream>>>(Z, 1024, 1024, csum, csumsq);
  bn_finalize<<<4,256,0,stream>>>(csum, csumsq, dec_g1, dec_be1, bscale, bshift, 1024);
  apply_act<<<CDIV(2048*1024,256),256,0,stream>>>(Z, 1024, 2048*1024, 1024,
      bscale, bshift, 0, nullptr, 0, h3b, 1024);

  // ---- decoder L2 -> decoded ----
  gemm_bf16_tn<<<dim3(16,27),256,0,stream>>>(h3b, dW2T, Z, 2048, 3456, 1024);
  zero_f32<<<CDIV(2*3456,256),256,0,stream>>>(csum, 2*3456);
  colstats<<<dim3(14,16),256,0,stream>>>(Z, 3456, 3372, csum, csumsq);
  bn_finalize<<<14,256,0,stream>>>(csum, csumsq, dec_g2, dec_be2, bscale, bshift, 3372);
  apply_act<<<CDIV(2048*3372,256),256,0,stream>>>(Z, 3456, 2048*3372, 3372,
      bscale, bshift, 0, dec_out, 3372, nullptr, 0);

  // ---- head ----
  gemm_small_f32<<<CDIV(2048*64,256),256,0,stream>>>(enc_out, out_W1, Z, 2048, 64, 256);
  zero_f32<<<CDIV(2*3456,256),256,0,stream>>>(csum, 2*3456);
  colstats<<<dim3(1,16),256,0,stream>>>(Z, 64, 64, csum, csumsq);
  bn_finalize<<<1,256,0,stream>>>(csum, csumsq, out_g1, out_be1, bscale, bshift, 64);
  apply_act<<<CDIV(2048*64,256),256,0,stream>>>(Z, 64, 2048*64, 64,
      bscale, bshift, 1, h5, 64, nullptr, 0);
  yfinal<<<8,256,0,stream>>>(h5, out_W2, out_b2, y_out);
}

// Round 3
// 518.386 us; speedup vs baseline: 1.3318x; 1.1285x over previous
//
#include <hip/hip_runtime.h>

#define CDIV(a,b) (((a)+(b)-1)/(b))

typedef __attribute__((ext_vector_type(8))) short bf16x8;
typedef __attribute__((ext_vector_type(4))) float f32x4;

__device__ __forceinline__ unsigned short f2b(float v) {
  union { float f; unsigned u; } x; x.f = v;
  unsigned r = x.u + 0x7FFFu + ((x.u >> 16) & 1u);
  return (unsigned short)(r >> 16);
}

__device__ __forceinline__ void gload_lds16(const void* g, void* l) {
  __builtin_amdgcn_global_load_lds(
      (const __attribute__((address_space(1))) unsigned int*)(g),
      (__attribute__((address_space(3))) unsigned int*)(l), 16, 0, 0);
}

// ---------------- MFMA bf16 GEMM 128x128: C[M,N] = A[M,K] * Bt[N,K]^T -------
__global__ __launch_bounds__(256) void gemm_bf16_tn(
    const unsigned short* __restrict__ A,
    const unsigned short* __restrict__ Bt,
    float* __restrict__ C,
    int M, int N, int K)
{
  __shared__ __align__(16) unsigned short As[128 * 64];
  __shared__ __align__(16) unsigned short Bs[128 * 64];
  const int tid = threadIdx.x;
  const int lane = tid & 63;
  const int wid = tid >> 6;
  const int wm = (wid >> 1) * 64;
  const int wn = (wid & 1) * 64;
  const long bm = (long)blockIdx.x * 128;
  const long bn = (long)blockIdx.y * 128;

  f32x4 acc[4][4] = {};

  const int lr = tid >> 3;
  const int lc = (tid & 7) * 8;

  for (int k0 = 0; k0 < K; k0 += 64) {
#pragma unroll
    for (int i = 0; i < 4; ++i) {
      const int row = i * 32 + lr;
      const int eoff = (i * 256 + tid) * 8;
      gload_lds16(A  + (bm + row) * (long)K + k0 + lc, As + eoff);
      gload_lds16(Bt + (bn + row) * (long)K + k0 + lc, Bs + eoff);
    }
    __syncthreads();
#pragma unroll
    for (int kk = 0; kk < 2; ++kk) {
      const int ko = kk * 32 + (lane >> 4) * 8;
      const int rsel = lane & 15;
      bf16x8 av[4], bv[4];
#pragma unroll
      for (int m = 0; m < 4; ++m)
        av[m] = *(const bf16x8*)(As + (wm + m * 16 + rsel) * 64 + ko);
#pragma unroll
      for (int n = 0; n < 4; ++n)
        bv[n] = *(const bf16x8*)(Bs + (wn + n * 16 + rsel) * 64 + ko);
#pragma unroll
      for (int m = 0; m < 4; ++m)
#pragma unroll
        for (int n = 0; n < 4; ++n)
          acc[m][n] = __builtin_amdgcn_mfma_f32_16x16x32_bf16(av[m], bv[n], acc[m][n], 0, 0, 0);
    }
    __syncthreads();
  }
  const int crow0 = (lane >> 4) * 4;
  const int ccol = lane & 15;
#pragma unroll
  for (int m = 0; m < 4; ++m)
#pragma unroll
    for (int n = 0; n < 4; ++n) {
      const long r = bm + wm + m * 16 + crow0;
      const long c = bn + wn + n * 16 + ccol;
#pragma unroll
      for (int q = 0; q < 4; ++q)
        C[(r + q) * (long)N + c] = acc[m][n][q];
    }
}

// ---------------- MFMA bf16 GEMM 64x128 (better occupancy for small grids) --
__global__ __launch_bounds__(256) void gemm64_bf16_tn(
    const unsigned short* __restrict__ A,
    const unsigned short* __restrict__ Bt,
    float* __restrict__ C,
    int M, int N, int K)
{
  __shared__ __align__(16) unsigned short As[64 * 64];
  __shared__ __align__(16) unsigned short Bs[128 * 64];
  const int tid = threadIdx.x;
  const int lane = tid & 63;
  const int wid = tid >> 6;
  const int wn = wid * 32;
  const long bm = (long)blockIdx.x * 64;
  const long bn = (long)blockIdx.y * 128;

  f32x4 acc[4][2] = {};

  const int lr = tid >> 3;
  const int lc = (tid & 7) * 8;

  for (int k0 = 0; k0 < K; k0 += 64) {
#pragma unroll
    for (int i = 0; i < 2; ++i) {
      const int row = i * 32 + lr;
      const int eoff = (i * 256 + tid) * 8;
      gload_lds16(A + (bm + row) * (long)K + k0 + lc, As + eoff);
    }
#pragma unroll
    for (int i = 0; i < 4; ++i) {
      const int row = i * 32 + lr;
      const int eoff = (i * 256 + tid) * 8;
      gload_lds16(Bt + (bn + row) * (long)K + k0 + lc, Bs + eoff);
    }
    __syncthreads();
#pragma unroll
    for (int kk = 0; kk < 2; ++kk) {
      const int ko = kk * 32 + (lane >> 4) * 8;
      const int rsel = lane & 15;
      bf16x8 av[4], bv[2];
#pragma unroll
      for (int m = 0; m < 4; ++m)
        av[m] = *(const bf16x8*)(As + (m * 16 + rsel) * 64 + ko);
#pragma unroll
      for (int n = 0; n < 2; ++n)
        bv[n] = *(const bf16x8*)(Bs + (wn + n * 16 + rsel) * 64 + ko);
#pragma unroll
      for (int m = 0; m < 4; ++m)
#pragma unroll
        for (int n = 0; n < 2; ++n)
          acc[m][n] = __builtin_amdgcn_mfma_f32_16x16x32_bf16(av[m], bv[n], acc[m][n], 0, 0, 0);
    }
    __syncthreads();
  }
  const int crow0 = (lane >> 4) * 4;
  const int ccol = lane & 15;
#pragma unroll
  for (int m = 0; m < 4; ++m)
#pragma unroll
    for (int n = 0; n < 2; ++n) {
      const long r = bm + m * 16 + crow0;
      const long c = bn + wn + n * 16 + ccol;
#pragma unroll
      for (int q = 0; q < 4; ++q)
        C[(r + q) * (long)N + c] = acc[m][n][q];
    }
}

// ---------------- small helpers ----------------
__global__ void zero_i32(int* p, int n) { int i = blockIdx.x*256+threadIdx.x; if (i < n) p[i] = 0; }
__global__ void zero_f32(float* p, int n) { int i = blockIdx.x*256+threadIdx.x; if (i < n) p[i] = 0.f; }
__global__ void fill_ones(float* p, int n) { int i = blockIdx.x*256+threadIdx.x; if (i < n) p[i] = 1.f; }

__global__ void deg_edges(const int* __restrict__ ei, const float* __restrict__ ew,
                          float* __restrict__ deg, int E) {
  int e = blockIdx.x*256+threadIdx.x;
  if (e < E) atomicAdd(&deg[ei[E + e]], ew[e]);
}
__global__ void make_dinv(float* p, int n) {
  int i = blockIdx.x*256+threadIdx.x; if (i < n) p[i] = rsqrtf(p[i]);
}
__global__ void flag_set(const int* __restrict__ idxa, int B_, int* __restrict__ flag) {
  int i = blockIdx.x*256+threadIdx.x; if (i < B_) flag[idxa[i]] = 1;
}
__global__ void flag_slot(int* __restrict__ flag, int n, int* __restrict__ ctr,
                          int* __restrict__ slotnode) {
  int i = blockIdx.x*256+threadIdx.x;
  if (i < n && flag[i]) {
    int s = atomicAdd(ctr, 1);
    flag[i] = s + 1;
    slotnode[s] = i;
  }
}
__global__ void hist_edges(const int* __restrict__ ei, const int* __restrict__ flag,
                           int* __restrict__ cnt, int E) {
  int e = blockIdx.x*256+threadIdx.x; if (e >= E) return;
  int s = flag[ei[E + e]];
  if (s) atomicAdd(&cnt[s - 1], 1);
}
// exclusive scan of cnt[0..2047] -> rowptr[0..2048], single block of 256
__global__ void scan2048(const int* __restrict__ cnt, int* __restrict__ rowptr) {
  __shared__ int part[256];
  int tid = threadIdx.x;
  int base = tid * 8;
  int vals[8]; int s = 0;
#pragma unroll
  for (int i = 0; i < 8; ++i) { vals[i] = s; s += cnt[base + i]; }
  part[tid] = s;
  __syncthreads();
  if (tid == 0) { int r = 0; for (int i = 0; i < 256; ++i) { int t = part[i]; part[i] = r; r += t; } }
  __syncthreads();
  int off = part[tid];
#pragma unroll
  for (int i = 0; i < 8; ++i) rowptr[base + i] = off + vals[i];
  if (tid == 255) rowptr[2048] = off + s;
}
__global__ void fill_edges(const int* __restrict__ ei, const float* __restrict__ ew,
                           const float* __restrict__ dinv, const int* __restrict__ flag,
                           const int* __restrict__ rowptr, int* __restrict__ fillp,
                           int* __restrict__ esrc, float* __restrict__ ecoef, int E) {
  int e = blockIdx.x*256+threadIdx.x; if (e >= E) return;
  int dst = ei[E + e];
  int s = flag[dst]; if (!s) return;
  int src = ei[e];
  int pos = rowptr[s - 1] + atomicAdd(&fillp[s - 1], 1);
  esrc[pos] = src;
  ecoef[pos] = ew[e] * dinv[src] * dinv[dst];
}
// per flagged dst: agg_b[slot] = bf16( dinv^2*X[node] + sum_e coef*X[src] )
__global__ void gather_agg(const float* __restrict__ X, const float* __restrict__ dinv,
                           const int* __restrict__ slotnode, const int* __restrict__ rowptr,
                           const int* __restrict__ esrc, const float* __restrict__ ecoef,
                           const int* __restrict__ nflag,
                           unsigned short* __restrict__ aggb, int K) {
  int s = blockIdx.x; if (s >= *nflag) return;
  int n = slotnode[s];
  float dn = dinv[n];
  float selfc = dn * dn;
  int e0 = rowptr[s], e1 = rowptr[s + 1];
  const float* xn = X + (long)n * K;
  unsigned short* ar = aggb + (long)s * K;
  for (int col = threadIdx.x; col < K; col += 256) {
    float acc = selfc * xn[col];
    for (int e = e0; e < e1; ++e)
      acc += ecoef[e] * X[(long)esrc[e] * K + col];
    ar[col] = f2b(acc);
  }
}
__global__ void gatherA(const unsigned short* __restrict__ aggb, const int* __restrict__ idxa,
                        const int* __restrict__ flag, unsigned short* __restrict__ Ab,
                        int K, int Kp) {
  int idx = blockIdx.x*256+threadIdx.x;
  if (idx >= 2048 * Kp) return;
  int b = idx / Kp, k = idx % Kp;
  Ab[idx] = (k < K) ? aggb[(long)(flag[idxa[b]] - 1) * K + k] : (unsigned short)0;
}

// Wt[Np][Kp] = bf16(W[K,N]^T), zero-padded
__global__ void transposeW(const float* __restrict__ W, unsigned short* __restrict__ Wt,
                           int K, int N, int Kp, int Np_) {
  __shared__ float tile[32][33];
  int k0 = blockIdx.x * 32, n0 = blockIdx.y * 32;
  for (int i = threadIdx.y; i < 32; i += 8) {
    int k = k0 + i, n = n0 + threadIdx.x;
    tile[i][threadIdx.x] = (k < K && n < N) ? W[(size_t)k * N + n] : 0.f;
  }
  __syncthreads();
  for (int i = threadIdx.y; i < 32; i += 8) {
    int n = n0 + i, k = k0 + threadIdx.x;
    if (n < Np_ && k < Kp) Wt[(size_t)n * Kp + k] = f2b(tile[threadIdx.x][i]);
  }
}

__global__ void colstats(const float* __restrict__ Z, int ldz, int cols,
                         float* __restrict__ csum, float* __restrict__ csumsq) {
  int col = blockIdx.x * 256 + threadIdx.x;
  if (col >= cols) return;
  int r0 = blockIdx.y * 128;
  float s = 0.f, s2 = 0.f;
  for (int r = r0; r < r0 + 128; ++r) {
    float v = Z[(long)r * ldz + col];
    s += v; s2 += v * v;
  }
  atomicAdd(&csum[col], s);
  atomicAdd(&csumsq[col], s2);
}

__global__ void bn_finalize(const float* __restrict__ csum, const float* __restrict__ csumsq,
                            const float* __restrict__ g, const float* __restrict__ beta,
                            float* __restrict__ scale, float* __restrict__ shift, int cols) {
  int j = blockIdx.x*256+threadIdx.x; if (j >= cols) return;
  const float invB = 1.f / 2048.f;
  float m = csum[j] * invB;
  float v = fmaxf(csumsq[j] * invB - m * m, 0.f);
  float sc = g[j] * rsqrtf(v + 1e-5f);
  scale[j] = sc;
  shift[j] = beta[j] - m * sc;
}

__global__ void apply_act(const float* __restrict__ Z, int ldz, int total, int cols,
                          const float* __restrict__ scale, const float* __restrict__ shift,
                          int leaky,
                          float* __restrict__ f32out, int ldf,
                          unsigned short* __restrict__ b16out, int ldb) {
  int idx = blockIdx.x*256+threadIdx.x;
  if (idx >= total) return;
  int b = idx / cols, j = idx % cols;
  float v = Z[(long)b * ldz + j];
  v = scale ? v * scale[j] + shift[j] : v + shift[j];
  v = (v >= 0.f) ? v : (leaky ? 0.01f * v : 0.f);
  if (f32out) f32out[(long)b * ldf + j] = v;
  if (b16out) b16out[(long)b * ldb + j] = f2b(v);
}

__global__ void feat_copy(const float* __restrict__ dv, const float* __restrict__ pe,
                          float* __restrict__ f32out, unsigned short* __restrict__ b16out) {
  int idx = blockIdx.x*256+threadIdx.x;
  if (idx >= 2048 * 1324) return;
  int b = idx / 1324, c = idx % 1324;
  float v = (c < 300) ? dv[b * 300 + c] : pe[(long)b * 1024 + (c - 300)];
  f32out[(long)b * 3372 + c] = v;
  b16out[(long)b * 3456 + c] = f2b(v);
}
__global__ void feat_pad(unsigned short* __restrict__ b16out) {
  int idx = blockIdx.x*256+threadIdx.x;
  if (idx >= 2048 * 84) return;
  int b = idx / 84, c = 3372 + idx % 84;
  b16out[(long)b * 3456 + c] = 0;
}

__global__ void yfinal(const float* __restrict__ h5, const float* __restrict__ W2,
                       const float* __restrict__ b2, float* __restrict__ y) {
  int b = blockIdx.x*256+threadIdx.x;
  if (b >= 2048) return;
  float s = b2[0];
  for (int k = 0; k < 64; ++k) s += h5[b * 64 + k] * W2[k];
  y[b] = s;
}

extern "C" void kernel_launch(void* const* d_in, const int* in_sizes, int n_in,
                              void* d_out, int out_size, void* d_ws, size_t ws_size,
                              hipStream_t stream) {
  (void)in_sizes; (void)n_in; (void)out_size; (void)ws_size;
  const int*   d_index = (const int*)d_in[0];
  const int*   p_index = (const int*)d_in[1];
  const float* d_vecs  = (const float*)d_in[2];
  const float* p_emb   = (const float*)d_in[3];
  const float* d_ecfps = (const float*)d_in[4];
  const int*   d_ei    = (const int*)d_in[5];
  const float* d_ew    = (const float*)d_in[6];
  const float* p_gos   = (const float*)d_in[7];
  const int*   p_ei    = (const int*)d_in[8];
  const float* p_ew    = (const float*)d_in[9];
  const float* d_gcn_W = (const float*)d_in[10];
  const float* d_gcn_b = (const float*)d_in[11];
  const float* p_gcn_W = (const float*)d_in[12];
  const float* p_gcn_b = (const float*)d_in[13];
  const float* enc_W1  = (const float*)d_in[14];
  const float* enc_g1  = (const float*)d_in[16];
  const float* enc_be1 = (const float*)d_in[17];
  const float* enc_W2  = (const float*)d_in[18];
  const float* enc_g2  = (const float*)d_in[20];
  const float* enc_be2 = (const float*)d_in[21];
  const float* dec_W1  = (const float*)d_in[22];
  const float* dec_g1  = (const float*)d_in[24];
  const float* dec_be1 = (const float*)d_in[25];
  const float* dec_W2  = (const float*)d_in[26];
  const float* dec_g2  = (const float*)d_in[28];
  const float* dec_be2 = (const float*)d_in[29];
  const float* out_W1  = (const float*)d_in[30];
  const float* out_g1  = (const float*)d_in[32];
  const float* out_be1 = (const float*)d_in[33];
  const float* out_W2  = (const float*)d_in[34];
  const float* out_b2  = (const float*)d_in[35];

  float* out = (float*)d_out;
  float* y_out    = out;
  float* enc_out  = out + 2048;
  float* dec_out  = out + 526336;
  float* feat_out = out + 7432192;

  char* ws = (char*)d_ws;
  size_t off = 0;
  auto alloc = [&](size_t bytes) {
    size_t o = off; off = (off + bytes + 255) & ~(size_t)255; return (void*)(ws + o);
  };
  int* iz = (int*)alloc((size_t)23194 * 4);
  int* flag_d = iz;              // 10000
  int* flag_p = iz + 10000;      // 5000
  int* cnt_d  = iz + 15000;      // 2048
  int* cnt_p  = iz + 17048;      // 2048
  int* fill_d = iz + 19096;      // 2048
  int* fill_p = iz + 21144;      // 2048
  int* ctr    = iz + 23192;      // 2
  int* slotnode_d = (int*)alloc(2048 * 4);
  int* slotnode_p = (int*)alloc(2048 * 4);
  int* rowptr_d = (int*)alloc(2049 * 4);
  int* rowptr_p = (int*)alloc(2049 * 4);
  int* esrc_d  = (int*)alloc((size_t)65536 * 4);
  float* ecoef_d = (float*)alloc((size_t)65536 * 4);
  int* esrc_p  = (int*)alloc((size_t)25000 * 4);
  float* ecoef_p = (float*)alloc((size_t)25000 * 4);
  float* deg   = (float*)alloc((size_t)15000 * 4);
  float* deg_d = deg;
  float* deg_p = deg + 10000;
  unsigned short* aggd_b = (unsigned short*)alloc((size_t)2048 * 1024 * 2);
  unsigned short* aggp_b = (unsigned short*)alloc((size_t)2048 * 2812 * 2);
  unsigned short* Adb   = (unsigned short*)alloc((size_t)2048 * 1024 * 2);
  unsigned short* Apb   = (unsigned short*)alloc((size_t)2048 * 2816 * 2);
  unsigned short* WdT   = (unsigned short*)alloc((size_t)1024 * 1024 * 2);
  unsigned short* WpT   = (unsigned short*)alloc((size_t)1024 * 2816 * 2);
  unsigned short* eW1T  = (unsigned short*)alloc((size_t)1024 * 3456 * 2);
  unsigned short* eW2T  = (unsigned short*)alloc((size_t)256 * 1024 * 2);
  unsigned short* dW1T  = (unsigned short*)alloc((size_t)1024 * 256 * 2);
  unsigned short* dW2T  = (unsigned short*)alloc((size_t)3456 * 1024 * 2);
  unsigned short* oW1T  = (unsigned short*)alloc((size_t)128 * 256 * 2);
  unsigned short* featb = (unsigned short*)alloc((size_t)2048 * 3456 * 2);
  float* Z    = (float*)alloc((size_t)2048 * 3456 * 4);
  unsigned short* h1b  = (unsigned short*)alloc((size_t)2048 * 1024 * 2);
  unsigned short* encb = (unsigned short*)alloc((size_t)2048 * 256 * 2);
  unsigned short* h3b  = (unsigned short*)alloc((size_t)2048 * 1024 * 2);
  float* h5   = (float*)alloc((size_t)2048 * 64 * 4);
  float* csum = (float*)alloc((size_t)2 * 3456 * 4);
  float* csumsq = csum + 3456;
  float* bscale = (float*)alloc((size_t)2 * 3456 * 4);
  float* bshift = bscale + 3456;

  // ---- GCN prep ----
  zero_i32<<<CDIV(23194,256),256,0,stream>>>(iz, 23194);
  fill_ones<<<CDIV(15000,256),256,0,stream>>>(deg, 15000);
  deg_edges<<<CDIV(65536,256),256,0,stream>>>(d_ei, d_ew, deg_d, 65536);
  deg_edges<<<CDIV(25000,256),256,0,stream>>>(p_ei, p_ew, deg_p, 25000);
  make_dinv<<<CDIV(15000,256),256,0,stream>>>(deg, 15000);
  flag_set<<<8,256,0,stream>>>(d_index, 2048, flag_d);
  flag_set<<<8,256,0,stream>>>(p_index, 2048, flag_p);
  flag_slot<<<CDIV(10000,256),256,0,stream>>>(flag_d, 10000, ctr, slotnode_d);
  flag_slot<<<CDIV(5000,256),256,0,stream>>>(flag_p, 5000, ctr + 1, slotnode_p);
  hist_edges<<<CDIV(65536,256),256,0,stream>>>(d_ei, flag_d, cnt_d, 65536);
  hist_edges<<<CDIV(25000,256),256,0,stream>>>(p_ei, flag_p, cnt_p, 25000);
  scan2048<<<1,256,0,stream>>>(cnt_d, rowptr_d);
  scan2048<<<1,256,0,stream>>>(cnt_p, rowptr_p);
  fill_edges<<<CDIV(65536,256),256,0,stream>>>(d_ei, d_ew, deg_d, flag_d, rowptr_d, fill_d,
                                               esrc_d, ecoef_d, 65536);
  fill_edges<<<CDIV(25000,256),256,0,stream>>>(p_ei, p_ew, deg_p, flag_p, rowptr_p, fill_p,
                                               esrc_p, ecoef_p, 25000);
  gather_agg<<<2048,256,0,stream>>>(d_ecfps, deg_d, slotnode_d, rowptr_d, esrc_d, ecoef_d,
                                    ctr, aggd_b, 1024);
  gather_agg<<<2048,256,0,stream>>>(p_gos, deg_p, slotnode_p, rowptr_p, esrc_p, ecoef_p,
                                    ctr + 1, aggp_b, 2812);
  gatherA<<<CDIV(2048*1024,256),256,0,stream>>>(aggd_b, d_index, flag_d, Adb, 1024, 1024);
  gatherA<<<CDIV(2048*2816,256),256,0,stream>>>(aggp_b, p_index, flag_p, Apb, 2812, 2816);

  // ---- weight transposes to bf16 [N,K] (padded) ----
  dim3 tb(32, 8);
  transposeW<<<dim3(32, 32), tb, 0, stream>>>(d_gcn_W, WdT, 1024, 1024, 1024, 1024);
  transposeW<<<dim3(88, 32), tb, 0, stream>>>(p_gcn_W, WpT, 2812, 1024, 2816, 1024);
  transposeW<<<dim3(108, 32), tb, 0, stream>>>(enc_W1, eW1T, 3372, 1024, 3456, 1024);
  transposeW<<<dim3(32, 8),  tb, 0, stream>>>(enc_W2, eW2T, 1024, 256, 1024, 256);
  transposeW<<<dim3(8, 32),  tb, 0, stream>>>(dec_W1, dW1T, 256, 1024, 256, 1024);
  transposeW<<<dim3(32, 108),tb, 0, stream>>>(dec_W2, dW2T, 1024, 3372, 1024, 3456);
  transposeW<<<dim3(8, 4),   tb, 0, stream>>>(out_W1, oW1T, 256, 64, 256, 128);

  // ---- GCN GEMMs -> feature ----
  gemm64_bf16_tn<<<dim3(32,8),256,0,stream>>>(Adb, WdT, Z, 2048, 1024, 1024);
  apply_act<<<CDIV(2048*1024,256),256,0,stream>>>(Z, 1024, 2048*1024, 1024,
      nullptr, d_gcn_b, 1, feat_out + 1324, 3372, featb + 1324, 3456);
  gemm64_bf16_tn<<<dim3(32,8),256,0,stream>>>(Apb, WpT, Z, 2048, 1024, 2816);
  apply_act<<<CDIV(2048*1024,256),256,0,stream>>>(Z, 1024, 2048*1024, 1024,
      nullptr, p_gcn_b, 1, feat_out + 2348, 3372, featb + 2348, 3456);
  feat_copy<<<CDIV(2048*1324,256),256,0,stream>>>(d_vecs, p_emb, feat_out, featb);
  feat_pad<<<CDIV(2048*84,256),256,0,stream>>>(featb);

  // ---- encoder L1 ----
  gemm64_bf16_tn<<<dim3(32,8),256,0,stream>>>(featb, eW1T, Z, 2048, 1024, 3456);
  zero_f32<<<CDIV(2*3456,256),256,0,stream>>>(csum, 2*3456);
  colstats<<<dim3(4,16),256,0,stream>>>(Z, 1024, 1024, csum, csumsq);
  bn_finalize<<<4,256,0,stream>>>(csum, csumsq, enc_g1, enc_be1, bscale, bshift, 1024);
  apply_act<<<CDIV(2048*1024,256),256,0,stream>>>(Z, 1024, 2048*1024, 1024,
      bscale, bshift, 0, nullptr, 0, h1b, 1024);

  // ---- encoder L2 -> encoded ----
  gemm64_bf16_tn<<<dim3(32,2),256,0,stream>>>(h1b, eW2T, Z, 2048, 256, 1024);
  zero_f32<<<CDIV(2*3456,256),256,0,stream>>>(csum, 2*3456);
  colstats<<<dim3(1,16),256,0,stream>>>(Z, 256, 256, csum, csumsq);
  bn_finalize<<<1,256,0,stream>>>(csum, csumsq, enc_g2, enc_be2, bscale, bshift, 256);
  apply_act<<<CDIV(2048*256,256),256,0,stream>>>(Z, 256, 2048*256, 256,
      bscale, bshift, 0, enc_out, 256, encb, 256);

  // ---- decoder L1 ----
  gemm64_bf16_tn<<<dim3(32,8),256,0,stream>>>(encb, dW1T, Z, 2048, 1024, 256);
  zero_f32<<<CDIV(2*3456,256),256,0,stream>>>(csum, 2*3456);
  colstats<<<dim3(4,16),256,0,stream>>>(Z, 1024, 1024, csum, csumsq);
  bn_finalize<<<4,256,0,stream>>>(csum, csumsq, dec_g1, dec_be1, bscale, bshift, 1024);
  apply_act<<<CDIV(2048*1024,256),256,0,stream>>>(Z, 1024, 2048*1024, 1024,
      bscale, bshift, 0, nullptr, 0, h3b, 1024);

  // ---- decoder L2 -> decoded ----
  gemm_bf16_tn<<<dim3(16,27),256,0,stream>>>(h3b, dW2T, Z, 2048, 3456, 1024);
  zero_f32<<<CDIV(2*3456,256),256,0,stream>>>(csum, 2*3456);
  colstats<<<dim3(14,16),256,0,stream>>>(Z, 3456, 3372, csum, csumsq);
  bn_finalize<<<14,256,0,stream>>>(csum, csumsq, dec_g2, dec_be2, bscale, bshift, 3372);
  apply_act<<<CDIV(2048*3372,256),256,0,stream>>>(Z, 3456, 2048*3372, 3372,
      bscale, bshift, 0, dec_out, 3372, nullptr, 0);

  // ---- head: MFMA on encb (never read d_out!) ----
  gemm64_bf16_tn<<<dim3(32,1),256,0,stream>>>(encb, oW1T, Z, 2048, 128, 256);
  zero_f32<<<CDIV(2*3456,256),256,0,stream>>>(csum, 2*3456);
  colstats<<<dim3(1,16),256,0,stream>>>(Z, 128, 64, csum, csumsq);
  bn_finalize<<<1,256,0,stream>>>(csum, csumsq, out_g1, out_be1, bscale, bshift, 64);
  apply_act<<<CDIV(2048*64,256),256,0,stream>>>(Z, 128, 2048*64, 64,
      bscale, bshift, 1, h5, 64, nullptr, 0);
  yfinal<<<8,256,0,stream>>>(h5, out_W2, out_b2, y_out);
}

// Round 4
// 463.735 us; speedup vs baseline: 1.4887x; 1.1179x over previous
//
#include <hip/hip_runtime.h>

#define CDIV(a,b) (((a)+(b)-1)/(b))

typedef __attribute__((ext_vector_type(8))) short bf16x8;
typedef __attribute__((ext_vector_type(4))) float f32x4;

__device__ __forceinline__ unsigned short f2b(float v) {
  union { float f; unsigned u; } x; x.f = v;
  unsigned r = x.u + 0x7FFFu + ((x.u >> 16) & 1u);
  return (unsigned short)(r >> 16);
}

__device__ __forceinline__ void gload_lds16(const void* g, void* l) {
  __builtin_amdgcn_global_load_lds(
      (const __attribute__((address_space(1))) unsigned int*)(g),
      (__attribute__((address_space(3))) unsigned int*)(l), 16, 0, 0);
}

// ---------------- MFMA bf16 GEMM 128x128: C[M,N] = A[M,K] * Bt[N,K]^T -------
__global__ __launch_bounds__(256) void gemm_bf16_tn(
    const unsigned short* __restrict__ A,
    const unsigned short* __restrict__ Bt,
    float* __restrict__ C,
    int M, int N, int K)
{
  __shared__ __align__(16) unsigned short As[128 * 64];
  __shared__ __align__(16) unsigned short Bs[128 * 64];
  const int tid = threadIdx.x;
  const int lane = tid & 63;
  const int wid = tid >> 6;
  const int wm = (wid >> 1) * 64;
  const int wn = (wid & 1) * 64;
  const long bm = (long)blockIdx.x * 128;
  const long bn = (long)blockIdx.y * 128;

  f32x4 acc[4][4] = {};

  const int lr = tid >> 3;
  const int lc = (tid & 7) * 8;

  for (int k0 = 0; k0 < K; k0 += 64) {
#pragma unroll
    for (int i = 0; i < 4; ++i) {
      const int row = i * 32 + lr;
      const int eoff = (i * 256 + tid) * 8;
      gload_lds16(A  + (bm + row) * (long)K + k0 + lc, As + eoff);
      gload_lds16(Bt + (bn + row) * (long)K + k0 + lc, Bs + eoff);
    }
    __syncthreads();
#pragma unroll
    for (int kk = 0; kk < 2; ++kk) {
      const int ko = kk * 32 + (lane >> 4) * 8;
      const int rsel = lane & 15;
      bf16x8 av[4], bv[4];
#pragma unroll
      for (int m = 0; m < 4; ++m)
        av[m] = *(const bf16x8*)(As + (wm + m * 16 + rsel) * 64 + ko);
#pragma unroll
      for (int n = 0; n < 4; ++n)
        bv[n] = *(const bf16x8*)(Bs + (wn + n * 16 + rsel) * 64 + ko);
#pragma unroll
      for (int m = 0; m < 4; ++m)
#pragma unroll
        for (int n = 0; n < 4; ++n)
          acc[m][n] = __builtin_amdgcn_mfma_f32_16x16x32_bf16(av[m], bv[n], acc[m][n], 0, 0, 0);
    }
    __syncthreads();
  }
  const int crow0 = (lane >> 4) * 4;
  const int ccol = lane & 15;
#pragma unroll
  for (int m = 0; m < 4; ++m)
#pragma unroll
    for (int n = 0; n < 4; ++n) {
      const long r = bm + wm + m * 16 + crow0;
      const long c = bn + wn + n * 16 + ccol;
#pragma unroll
      for (int q = 0; q < 4; ++q)
        C[(r + q) * (long)N + c] = acc[m][n][q];
    }
}

// ---------------- MFMA bf16 GEMM 64x128 (better occupancy for small grids) --
__global__ __launch_bounds__(256) void gemm64_bf16_tn(
    const unsigned short* __restrict__ A,
    const unsigned short* __restrict__ Bt,
    float* __restrict__ C,
    int M, int N, int K)
{
  __shared__ __align__(16) unsigned short As[64 * 64];
  __shared__ __align__(16) unsigned short Bs[128 * 64];
  const int tid = threadIdx.x;
  const int lane = tid & 63;
  const int wid = tid >> 6;
  const int wn = wid * 32;
  const long bm = (long)blockIdx.x * 64;
  const long bn = (long)blockIdx.y * 128;

  f32x4 acc[4][2] = {};

  const int lr = tid >> 3;
  const int lc = (tid & 7) * 8;

  for (int k0 = 0; k0 < K; k0 += 64) {
#pragma unroll
    for (int i = 0; i < 2; ++i) {
      const int row = i * 32 + lr;
      const int eoff = (i * 256 + tid) * 8;
      gload_lds16(A + (bm + row) * (long)K + k0 + lc, As + eoff);
    }
#pragma unroll
    for (int i = 0; i < 4; ++i) {
      const int row = i * 32 + lr;
      const int eoff = (i * 256 + tid) * 8;
      gload_lds16(Bt + (bn + row) * (long)K + k0 + lc, Bs + eoff);
    }
    __syncthreads();
#pragma unroll
    for (int kk = 0; kk < 2; ++kk) {
      const int ko = kk * 32 + (lane >> 4) * 8;
      const int rsel = lane & 15;
      bf16x8 av[4], bv[2];
#pragma unroll
      for (int m = 0; m < 4; ++m)
        av[m] = *(const bf16x8*)(As + (m * 16 + rsel) * 64 + ko);
#pragma unroll
      for (int n = 0; n < 2; ++n)
        bv[n] = *(const bf16x8*)(Bs + (wn + n * 16 + rsel) * 64 + ko);
#pragma unroll
      for (int m = 0; m < 4; ++m)
#pragma unroll
        for (int n = 0; n < 2; ++n)
          acc[m][n] = __builtin_amdgcn_mfma_f32_16x16x32_bf16(av[m], bv[n], acc[m][n], 0, 0, 0);
    }
    __syncthreads();
  }
  const int crow0 = (lane >> 4) * 4;
  const int ccol = lane & 15;
#pragma unroll
  for (int m = 0; m < 4; ++m)
#pragma unroll
    for (int n = 0; n < 2; ++n) {
      const long r = bm + m * 16 + crow0;
      const long c = bn + wn + n * 16 + ccol;
#pragma unroll
      for (int q = 0; q < 4; ++q)
        C[(r + q) * (long)N + c] = acc[m][n][q];
    }
}

// ---------------- small helpers ----------------
__global__ void zero_i32(int* p, int n) { int i = blockIdx.x*256+threadIdx.x; if (i < n) p[i] = 0; }
__global__ void zero_f32(float* p, int n) { int i = blockIdx.x*256+threadIdx.x; if (i < n) p[i] = 0.f; }
__global__ void fill_ones(float* p, int n) { int i = blockIdx.x*256+threadIdx.x; if (i < n) p[i] = 1.f; }

__global__ void deg_edges(const int* __restrict__ ei, const float* __restrict__ ew,
                          float* __restrict__ deg, int E) {
  int e = blockIdx.x*256+threadIdx.x;
  if (e < E) atomicAdd(&deg[ei[E + e]], ew[e]);
}
__global__ void make_dinv(float* p, int n) {
  int i = blockIdx.x*256+threadIdx.x; if (i < n) p[i] = rsqrtf(p[i]);
}
__global__ void flag_set(const int* __restrict__ idxa, int B_, int* __restrict__ flag) {
  int i = blockIdx.x*256+threadIdx.x; if (i < B_) flag[idxa[i]] = 1;
}
__global__ void flag_slot(int* __restrict__ flag, int n, int* __restrict__ ctr,
                          int* __restrict__ slotnode) {
  int i = blockIdx.x*256+threadIdx.x;
  if (i < n && flag[i]) {
    int s = atomicAdd(ctr, 1);
    flag[i] = s + 1;
    slotnode[s] = i;
  }
}
__global__ void hist_edges(const int* __restrict__ ei, const int* __restrict__ flag,
                           int* __restrict__ cnt, int E) {
  int e = blockIdx.x*256+threadIdx.x; if (e >= E) return;
  int s = flag[ei[E + e]];
  if (s) atomicAdd(&cnt[s - 1], 1);
}
// exclusive scan of cnt[0..2047] -> rowptr[0..2048], single block of 256
__global__ void scan2048(const int* __restrict__ cnt, int* __restrict__ rowptr) {
  __shared__ int part[256];
  int tid = threadIdx.x;
  int base = tid * 8;
  int vals[8]; int s = 0;
#pragma unroll
  for (int i = 0; i < 8; ++i) { vals[i] = s; s += cnt[base + i]; }
  part[tid] = s;
  __syncthreads();
  if (tid == 0) { int r = 0; for (int i = 0; i < 256; ++i) { int t = part[i]; part[i] = r; r += t; } }
  __syncthreads();
  int off = part[tid];
#pragma unroll
  for (int i = 0; i < 8; ++i) rowptr[base + i] = off + vals[i];
  if (tid == 255) rowptr[2048] = off + s;
}
__global__ void fill_edges(const int* __restrict__ ei, const float* __restrict__ ew,
                           const float* __restrict__ dinv, const int* __restrict__ flag,
                           const int* __restrict__ rowptr, int* __restrict__ fillp,
                           int* __restrict__ esrc, float* __restrict__ ecoef, int E) {
  int e = blockIdx.x*256+threadIdx.x; if (e >= E) return;
  int dst = ei[E + e];
  int s = flag[dst]; if (!s) return;
  int src = ei[e];
  int pos = rowptr[s - 1] + atomicAdd(&fillp[s - 1], 1);
  esrc[pos] = src;
  ecoef[pos] = ew[e] * dinv[src] * dinv[dst];
}

// fused dual-graph gather: blocks [0,2048) = d-graph, [2048,4096) = p-graph.
// LDS-staged edge lists, float4 columns, register accumulators.
__global__ __launch_bounds__(256) void gather_agg2(
    const float* __restrict__ Xd, const float* __restrict__ dinv_d,
    const int* __restrict__ slot_d, const int* __restrict__ rp_d,
    const int* __restrict__ es_d, const float* __restrict__ ec_d,
    const int* __restrict__ nflag_d, unsigned short* __restrict__ aggd, int Kd,
    const float* __restrict__ Xp, const float* __restrict__ dinv_p,
    const int* __restrict__ slot_p, const int* __restrict__ rp_p,
    const int* __restrict__ es_p, const float* __restrict__ ec_p,
    const int* __restrict__ nflag_p, unsigned short* __restrict__ aggp, int Kp)
{
  __shared__ int   s_src[512];
  __shared__ float s_coef[512];
  const int tid = threadIdx.x;
  const bool isP = blockIdx.x >= 2048;
  const int s = isP ? (int)blockIdx.x - 2048 : (int)blockIdx.x;
  const float* X      = isP ? Xp : Xd;
  const float* dinv   = isP ? dinv_p : dinv_d;
  const int*   slot   = isP ? slot_p : slot_d;
  const int*   rp     = isP ? rp_p : rp_d;
  const int*   es     = isP ? es_p : es_d;
  const float* ec     = isP ? ec_p : ec_d;
  const int    nflag  = isP ? *nflag_p : *nflag_d;
  unsigned short* agg = isP ? aggp : aggd;
  const int    K      = isP ? Kp : Kd;
  if (s >= nflag) return;

  const int n = slot[s];
  const float dn = dinv[n];
  const float selfc = dn * dn;
  const int e0 = rp[s], e1 = rp[s + 1];
  const int K4 = K >> 2;                       // 256 (d) or 703 (p)
  const float4* xn = (const float4*)(X + (long)n * K);

  float4 acc[3];
  int ncols = 0;
#pragma unroll
  for (int j = 0; j < 3; ++j) {
    int c = tid + j * 256;
    if (c < K4) {
      float4 v = xn[c];
      acc[j] = make_float4(selfc * v.x, selfc * v.y, selfc * v.z, selfc * v.w);
      ncols = j + 1;
    }
  }

  for (int base = e0; base < e1; base += 512) {
    int cnt = min(512, e1 - base);
    __syncthreads();
    for (int i = tid; i < cnt; i += 256) { s_src[i] = es[base + i]; s_coef[i] = ec[base + i]; }
    __syncthreads();
#pragma unroll 4
    for (int e = 0; e < cnt; ++e) {
      const float4* xr = (const float4*)(X + (long)s_src[e] * K);
      const float cf = s_coef[e];
#pragma unroll
      for (int j = 0; j < 3; ++j) {
        int c = tid + j * 256;
        if (j < ncols) {
          float4 v = xr[c];
          acc[j].x += cf * v.x; acc[j].y += cf * v.y;
          acc[j].z += cf * v.z; acc[j].w += cf * v.w;
        }
      }
    }
  }

  unsigned short* ar = agg + (long)s * K;
#pragma unroll
  for (int j = 0; j < 3; ++j) {
    int c = tid + j * 256;
    if (j < ncols) {
      ushort4 o;
      o.x = f2b(acc[j].x); o.y = f2b(acc[j].y);
      o.z = f2b(acc[j].z); o.w = f2b(acc[j].w);
      *(ushort4*)(ar + 4 * c) = o;
    }
  }
}

__global__ void gatherA(const unsigned short* __restrict__ aggb, const int* __restrict__ idxa,
                        const int* __restrict__ flag, unsigned short* __restrict__ Ab,
                        int K, int Kp) {
  int idx = blockIdx.x*256+threadIdx.x;
  if (idx >= 2048 * Kp) return;
  int b = idx / Kp, k = idx % Kp;
  Ab[idx] = (k < K) ? aggb[(long)(flag[idxa[b]] - 1) * K + k] : (unsigned short)0;
}

// Wt[Np][Kp] = bf16(W[K,N]^T), zero-padded
__global__ void transposeW(const float* __restrict__ W, unsigned short* __restrict__ Wt,
                           int K, int N, int Kp, int Np_) {
  __shared__ float tile[32][33];
  int k0 = blockIdx.x * 32, n0 = blockIdx.y * 32;
  for (int i = threadIdx.y; i < 32; i += 8) {
    int k = k0 + i, n = n0 + threadIdx.x;
    tile[i][threadIdx.x] = (k < K && n < N) ? W[(size_t)k * N + n] : 0.f;
  }
  __syncthreads();
  for (int i = threadIdx.y; i < 32; i += 8) {
    int n = n0 + i, k = k0 + threadIdx.x;
    if (n < Np_ && k < Kp) Wt[(size_t)n * Kp + k] = f2b(tile[threadIdx.x][i]);
  }
}

__global__ void colstats(const float* __restrict__ Z, int ldz, int cols,
                         float* __restrict__ csum, float* __restrict__ csumsq) {
  int col = blockIdx.x * 256 + threadIdx.x;
  if (col >= cols) return;
  int r0 = blockIdx.y * 128;
  float s = 0.f, s2 = 0.f;
  for (int r = r0; r < r0 + 128; ++r) {
    float v = Z[(long)r * ldz + col];
    s += v; s2 += v * v;
  }
  atomicAdd(&csum[col], s);
  atomicAdd(&csumsq[col], s2);
}

__global__ void bn_finalize(const float* __restrict__ csum, const float* __restrict__ csumsq,
                            const float* __restrict__ g, const float* __restrict__ beta,
                            float* __restrict__ scale, float* __restrict__ shift, int cols) {
  int j = blockIdx.x*256+threadIdx.x; if (j >= cols) return;
  const float invB = 1.f / 2048.f;
  float m = csum[j] * invB;
  float v = fmaxf(csumsq[j] * invB - m * m, 0.f);
  float sc = g[j] * rsqrtf(v + 1e-5f);
  scale[j] = sc;
  shift[j] = beta[j] - m * sc;
}

__global__ void apply_act(const float* __restrict__ Z, int ldz, int total, int cols,
                          const float* __restrict__ scale, const float* __restrict__ shift,
                          int leaky,
                          float* __restrict__ f32out, int ldf,
                          unsigned short* __restrict__ b16out, int ldb) {
  int idx = blockIdx.x*256+threadIdx.x;
  if (idx >= total) return;
  int b = idx / cols, j = idx % cols;
  float v = Z[(long)b * ldz + j];
  v = scale ? v * scale[j] + shift[j] : v + shift[j];
  v = (v >= 0.f) ? v : (leaky ? 0.01f * v : 0.f);
  if (f32out) f32out[(long)b * ldf + j] = v;
  if (b16out) b16out[(long)b * ldb + j] = f2b(v);
}

__global__ void feat_copy(const float* __restrict__ dv, const float* __restrict__ pe,
                          float* __restrict__ f32out, unsigned short* __restrict__ b16out) {
  int idx = blockIdx.x*256+threadIdx.x;
  if (idx >= 2048 * 1324) return;
  int b = idx / 1324, c = idx % 1324;
  float v = (c < 300) ? dv[b * 300 + c] : pe[(long)b * 1024 + (c - 300)];
  f32out[(long)b * 3372 + c] = v;
  b16out[(long)b * 3456 + c] = f2b(v);
}
__global__ void feat_pad(unsigned short* __restrict__ b16out) {
  int idx = blockIdx.x*256+threadIdx.x;
  if (idx >= 2048 * 84) return;
  int b = idx / 84, c = 3372 + idx % 84;
  b16out[(long)b * 3456 + c] = 0;
}

__global__ void yfinal(const float* __restrict__ h5, const float* __restrict__ W2,
                       const float* __restrict__ b2, float* __restrict__ y) {
  int b = blockIdx.x*256+threadIdx.x;
  if (b >= 2048) return;
  float s = b2[0];
  for (int k = 0; k < 64; ++k) s += h5[b * 64 + k] * W2[k];
  y[b] = s;
}

extern "C" void kernel_launch(void* const* d_in, const int* in_sizes, int n_in,
                              void* d_out, int out_size, void* d_ws, size_t ws_size,
                              hipStream_t stream) {
  (void)in_sizes; (void)n_in; (void)out_size; (void)ws_size;
  const int*   d_index = (const int*)d_in[0];
  const int*   p_index = (const int*)d_in[1];
  const float* d_vecs  = (const float*)d_in[2];
  const float* p_emb   = (const float*)d_in[3];
  const float* d_ecfps = (const float*)d_in[4];
  const int*   d_ei    = (const int*)d_in[5];
  const float* d_ew    = (const float*)d_in[6];
  const float* p_gos   = (const float*)d_in[7];
  const int*   p_ei    = (const int*)d_in[8];
  const float* p_ew    = (const float*)d_in[9];
  const float* d_gcn_W = (const float*)d_in[10];
  const float* d_gcn_b = (const float*)d_in[11];
  const float* p_gcn_W = (const float*)d_in[12];
  const float* p_gcn_b = (const float*)d_in[13];
  const float* enc_W1  = (const float*)d_in[14];
  const float* enc_g1  = (const float*)d_in[16];
  const float* enc_be1 = (const float*)d_in[17];
  const float* enc_W2  = (const float*)d_in[18];
  const float* enc_g2  = (const float*)d_in[20];
  const float* enc_be2 = (const float*)d_in[21];
  const float* dec_W1  = (const float*)d_in[22];
  const float* dec_g1  = (const float*)d_in[24];
  const float* dec_be1 = (const float*)d_in[25];
  const float* dec_W2  = (const float*)d_in[26];
  const float* dec_g2  = (const float*)d_in[28];
  const float* dec_be2 = (const float*)d_in[29];
  const float* out_W1  = (const float*)d_in[30];
  const float* out_g1  = (const float*)d_in[32];
  const float* out_be1 = (const float*)d_in[33];
  const float* out_W2  = (const float*)d_in[34];
  const float* out_b2  = (const float*)d_in[35];

  float* out = (float*)d_out;
  float* y_out    = out;
  float* enc_out  = out + 2048;
  float* dec_out  = out + 526336;
  float* feat_out = out + 7432192;

  char* ws = (char*)d_ws;
  size_t off = 0;
  auto alloc = [&](size_t bytes) {
    size_t o = off; off = (off + bytes + 255) & ~(size_t)255; return (void*)(ws + o);
  };
  int* iz = (int*)alloc((size_t)23194 * 4);
  int* flag_d = iz;              // 10000
  int* flag_p = iz + 10000;      // 5000
  int* cnt_d  = iz + 15000;      // 2048
  int* cnt_p  = iz + 17048;      // 2048
  int* fill_d = iz + 19096;      // 2048
  int* fill_p = iz + 21144;      // 2048
  int* ctr    = iz + 23192;      // 2
  int* slotnode_d = (int*)alloc(2048 * 4);
  int* slotnode_p = (int*)alloc(2048 * 4);
  int* rowptr_d = (int*)alloc(2049 * 4);
  int* rowptr_p = (int*)alloc(2049 * 4);
  int* esrc_d  = (int*)alloc((size_t)65536 * 4);
  float* ecoef_d = (float*)alloc((size_t)65536 * 4);
  int* esrc_p  = (int*)alloc((size_t)25000 * 4);
  float* ecoef_p = (float*)alloc((size_t)25000 * 4);
  float* deg   = (float*)alloc((size_t)15000 * 4);
  float* deg_d = deg;
  float* deg_p = deg + 10000;
  unsigned short* aggd_b = (unsigned short*)alloc((size_t)2048 * 1024 * 2);
  unsigned short* aggp_b = (unsigned short*)alloc((size_t)2048 * 2812 * 2);
  unsigned short* Adb   = (unsigned short*)alloc((size_t)2048 * 1024 * 2);
  unsigned short* Apb   = (unsigned short*)alloc((size_t)2048 * 2816 * 2);
  unsigned short* WdT   = (unsigned short*)alloc((size_t)1024 * 1024 * 2);
  unsigned short* WpT   = (unsigned short*)alloc((size_t)1024 * 2816 * 2);
  unsigned short* eW1T  = (unsigned short*)alloc((size_t)1024 * 3456 * 2);
  unsigned short* eW2T  = (unsigned short*)alloc((size_t)256 * 1024 * 2);
  unsigned short* dW1T  = (unsigned short*)alloc((size_t)1024 * 256 * 2);
  unsigned short* dW2T  = (unsigned short*)alloc((size_t)3456 * 1024 * 2);
  unsigned short* oW1T  = (unsigned short*)alloc((size_t)128 * 256 * 2);
  unsigned short* featb = (unsigned short*)alloc((size_t)2048 * 3456 * 2);
  float* Z    = (float*)alloc((size_t)2048 * 3456 * 4);
  unsigned short* h1b  = (unsigned short*)alloc((size_t)2048 * 1024 * 2);
  unsigned short* encb = (unsigned short*)alloc((size_t)2048 * 256 * 2);
  unsigned short* h3b  = (unsigned short*)alloc((size_t)2048 * 1024 * 2);
  float* h5   = (float*)alloc((size_t)2048 * 64 * 4);
  float* csum = (float*)alloc((size_t)2 * 3456 * 4);
  float* csumsq = csum + 3456;
  float* bscale = (float*)alloc((size_t)2 * 3456 * 4);
  float* bshift = bscale + 3456;

  // ---- GCN prep ----
  zero_i32<<<CDIV(23194,256),256,0,stream>>>(iz, 23194);
  fill_ones<<<CDIV(15000,256),256,0,stream>>>(deg, 15000);
  deg_edges<<<CDIV(65536,256),256,0,stream>>>(d_ei, d_ew, deg_d, 65536);
  deg_edges<<<CDIV(25000,256),256,0,stream>>>(p_ei, p_ew, deg_p, 25000);
  make_dinv<<<CDIV(15000,256),256,0,stream>>>(deg, 15000);
  flag_set<<<8,256,0,stream>>>(d_index, 2048, flag_d);
  flag_set<<<8,256,0,stream>>>(p_index, 2048, flag_p);
  flag_slot<<<CDIV(10000,256),256,0,stream>>>(flag_d, 10000, ctr, slotnode_d);
  flag_slot<<<CDIV(5000,256),256,0,stream>>>(flag_p, 5000, ctr + 1, slotnode_p);
  hist_edges<<<CDIV(65536,256),256,0,stream>>>(d_ei, flag_d, cnt_d, 65536);
  hist_edges<<<CDIV(25000,256),256,0,stream>>>(p_ei, flag_p, cnt_p, 25000);
  scan2048<<<1,256,0,stream>>>(cnt_d, rowptr_d);
  scan2048<<<1,256,0,stream>>>(cnt_p, rowptr_p);
  fill_edges<<<CDIV(65536,256),256,0,stream>>>(d_ei, d_ew, deg_d, flag_d, rowptr_d, fill_d,
                                               esrc_d, ecoef_d, 65536);
  fill_edges<<<CDIV(25000,256),256,0,stream>>>(p_ei, p_ew, deg_p, flag_p, rowptr_p, fill_p,
                                               esrc_p, ecoef_p, 25000);
  gather_agg2<<<4096,256,0,stream>>>(
      d_ecfps, deg_d, slotnode_d, rowptr_d, esrc_d, ecoef_d, ctr, aggd_b, 1024,
      p_gos,   deg_p, slotnode_p, rowptr_p, esrc_p, ecoef_p, ctr + 1, aggp_b, 2812);
  gatherA<<<CDIV(2048*1024,256),256,0,stream>>>(aggd_b, d_index, flag_d, Adb, 1024, 1024);
  gatherA<<<CDIV(2048*2816,256),256,0,stream>>>(aggp_b, p_index, flag_p, Apb, 2812, 2816);

  // ---- weight transposes to bf16 [N,K] (padded) ----
  dim3 tb(32, 8);
  transposeW<<<dim3(32, 32), tb, 0, stream>>>(d_gcn_W, WdT, 1024, 1024, 1024, 1024);
  transposeW<<<dim3(88, 32), tb, 0, stream>>>(p_gcn_W, WpT, 2812, 1024, 2816, 1024);
  transposeW<<<dim3(108, 32), tb, 0, stream>>>(enc_W1, eW1T, 3372, 1024, 3456, 1024);
  transposeW<<<dim3(32, 8),  tb, 0, stream>>>(enc_W2, eW2T, 1024, 256, 1024, 256);
  transposeW<<<dim3(8, 32),  tb, 0, stream>>>(dec_W1, dW1T, 256, 1024, 256, 1024);
  transposeW<<<dim3(32, 108),tb, 0, stream>>>(dec_W2, dW2T, 1024, 3372, 1024, 3456);
  transposeW<<<dim3(8, 4),   tb, 0, stream>>>(out_W1, oW1T, 256, 64, 256, 128);

  // ---- GCN GEMMs -> feature ----
  gemm64_bf16_tn<<<dim3(32,8),256,0,stream>>>(Adb, WdT, Z, 2048, 1024, 1024);
  apply_act<<<CDIV(2048*1024,256),256,0,stream>>>(Z, 1024, 2048*1024, 1024,
      nullptr, d_gcn_b, 1, feat_out + 1324, 3372, featb + 1324, 3456);
  gemm64_bf16_tn<<<dim3(32,8),256,0,stream>>>(Apb, WpT, Z, 2048, 1024, 2816);
  apply_act<<<CDIV(2048*1024,256),256,0,stream>>>(Z, 1024, 2048*1024, 1024,
      nullptr, p_gcn_b, 1, feat_out + 2348, 3372, featb + 2348, 3456);
  feat_copy<<<CDIV(2048*1324,256),256,0,stream>>>(d_vecs, p_emb, feat_out, featb);
  feat_pad<<<CDIV(2048*84,256),256,0,stream>>>(featb);

  // ---- encoder L1 ----
  gemm64_bf16_tn<<<dim3(32,8),256,0,stream>>>(featb, eW1T, Z, 2048, 1024, 3456);
  zero_f32<<<CDIV(2*3456,256),256,0,stream>>>(csum, 2*3456);
  colstats<<<dim3(4,16),256,0,stream>>>(Z, 1024, 1024, csum, csumsq);
  bn_finalize<<<4,256,0,stream>>>(csum, csumsq, enc_g1, enc_be1, bscale, bshift, 1024);
  apply_act<<<CDIV(2048*1024,256),256,0,stream>>>(Z, 1024, 2048*1024, 1024,
      bscale, bshift, 0, nullptr, 0, h1b, 1024);

  // ---- encoder L2 -> encoded ----
  gemm64_bf16_tn<<<dim3(32,2),256,0,stream>>>(h1b, eW2T, Z, 2048, 256, 1024);
  zero_f32<<<CDIV(2*3456,256),256,0,stream>>>(csum, 2*3456);
  colstats<<<dim3(1,16),256,0,stream>>>(Z, 256, 256, csum, csumsq);
  bn_finalize<<<1,256,0,stream>>>(csum, csumsq, enc_g2, enc_be2, bscale, bshift, 256);
  apply_act<<<CDIV(2048*256,256),256,0,stream>>>(Z, 256, 2048*256, 256,
      bscale, bshift, 0, enc_out, 256, encb, 256);

  // ---- decoder L1 ----
  gemm64_bf16_tn<<<dim3(32,8),256,0,stream>>>(encb, dW1T, Z, 2048, 1024, 256);
  zero_f32<<<CDIV(2*3456,256),256,0,stream>>>(csum, 2*3456);
  colstats<<<dim3(4,16),256,0,stream>>>(Z, 1024, 1024, csum, csumsq);
  bn_finalize<<<4,256,0,stream>>>(csum, csumsq, dec_g1, dec_be1, bscale, bshift, 1024);
  apply_act<<<CDIV(2048*1024,256),256,0,stream>>>(Z, 1024, 2048*1024, 1024,
      bscale, bshift, 0, nullptr, 0, h3b, 1024);

  // ---- decoder L2 -> decoded ----
  gemm_bf16_tn<<<dim3(16,27),256,0,stream>>>(h3b, dW2T, Z, 2048, 3456, 1024);
  zero_f32<<<CDIV(2*3456,256),256,0,stream>>>(csum, 2*3456);
  colstats<<<dim3(14,16),256,0,stream>>>(Z, 3456, 3372, csum, csumsq);
  bn_finalize<<<14,256,0,stream>>>(csum, csumsq, dec_g2, dec_be2, bscale, bshift, 3372);
  apply_act<<<CDIV(2048*3372,256),256,0,stream>>>(Z, 3456, 2048*3372, 3372,
      bscale, bshift, 0, dec_out, 3372, nullptr, 0);

  // ---- head: MFMA on encb (never read d_out!) ----
  gemm64_bf16_tn<<<dim3(32,1),256,0,stream>>>(encb, oW1T, Z, 2048, 128, 256);
  zero_f32<<<CDIV(2*3456,256),256,0,stream>>>(csum, 2*3456);
  colstats<<<dim3(1,16),256,0,stream>>>(Z, 128, 64, csum, csumsq);
  bn_finalize<<<1,256,0,stream>>>(csum, csumsq, out_g1, out_be1, bscale, bshift, 64);
  apply_act<<<CDIV(2048*64,256),256,0,stream>>>(Z, 128, 2048*64, 64,
      bscale, bshift, 1, h5, 64, nullptr, 0);
  yfinal<<<8,256,0,stream>>>(h5, out_W2, out_b2, y_out);
}

// Round 5
// 433.815 us; speedup vs baseline: 1.5914x; 1.0690x over previous
//
#include <hip/hip_runtime.h>

#define CDIV(a,b) (((a)+(b)-1)/(b))

typedef __attribute__((ext_vector_type(8))) short bf16x8;
typedef __attribute__((ext_vector_type(4))) float f32x4;

__device__ __forceinline__ unsigned short f2b(float v) {
  union { float f; unsigned u; } x; x.f = v;
  unsigned r = x.u + 0x7FFFu + ((x.u >> 16) & 1u);
  return (unsigned short)(r >> 16);
}

__device__ __forceinline__ void gload_lds16(const void* g, void* l) {
  __builtin_amdgcn_global_load_lds(
      (const __attribute__((address_space(1))) unsigned int*)(g),
      (__attribute__((address_space(3))) unsigned int*)(l), 16, 0, 0);
}

// ---------------- MFMA bf16 GEMM 128x128, XOR-swizzled LDS ------------------
// LDS slot [row][c8] holds logical [row][c8 ^ (row&7)] (16B granules).
// Staged via pre-swizzled GLOBAL source (linear LDS dest, rule #21).
__global__ __launch_bounds__(256) void gemm_bf16_tn(
    const unsigned short* __restrict__ A,
    const unsigned short* __restrict__ Bt,
    float* __restrict__ C,
    int M, int N, int K)
{
  __shared__ __align__(16) unsigned short As[128 * 64];
  __shared__ __align__(16) unsigned short Bs[128 * 64];
  const int tid = threadIdx.x;
  const int lane = tid & 63;
  const int wid = tid >> 6;
  const int wm = (wid >> 1) * 64;
  const int wn = (wid & 1) * 64;
  const long bm = (long)blockIdx.x * 128;
  const long bn = (long)blockIdx.y * 128;

  f32x4 acc[4][4] = {};

  const int lr = tid >> 3;                        // row within 32-chunk
  const int lc = (((tid & 7) ^ (lr & 7)) * 8);    // swizzled source col

  for (int k0 = 0; k0 < K; k0 += 64) {
#pragma unroll
    for (int i = 0; i < 4; ++i) {
      const int row = i * 32 + lr;
      const int eoff = (i * 256 + tid) * 8;
      gload_lds16(A  + (bm + row) * (long)K + k0 + lc, As + eoff);
      gload_lds16(Bt + (bn + row) * (long)K + k0 + lc, Bs + eoff);
    }
    __syncthreads();
#pragma unroll
    for (int kk = 0; kk < 2; ++kk) {
      const int rsel = lane & 15;
      const int rx = rsel & 7;
      const int ko8 = kk * 4 + (lane >> 4);
      const int koz = ((ko8 ^ rx) << 3);
      bf16x8 av[4], bv[4];
#pragma unroll
      for (int m = 0; m < 4; ++m)
        av[m] = *(const bf16x8*)(As + (wm + m * 16 + rsel) * 64 + koz);
#pragma unroll
      for (int n = 0; n < 4; ++n)
        bv[n] = *(const bf16x8*)(Bs + (wn + n * 16 + rsel) * 64 + koz);
#pragma unroll
      for (int m = 0; m < 4; ++m)
#pragma unroll
        for (int n = 0; n < 4; ++n)
          acc[m][n] = __builtin_amdgcn_mfma_f32_16x16x32_bf16(av[m], bv[n], acc[m][n], 0, 0, 0);
    }
    __syncthreads();
  }
  const int crow0 = (lane >> 4) * 4;
  const int ccol = lane & 15;
#pragma unroll
  for (int m = 0; m < 4; ++m)
#pragma unroll
    for (int n = 0; n < 4; ++n) {
      const long r = bm + wm + m * 16 + crow0;
      const long c = bn + wn + n * 16 + ccol;
#pragma unroll
      for (int q = 0; q < 4; ++q)
        C[(r + q) * (long)N + c] = acc[m][n][q];
    }
}

// ---------------- MFMA bf16 GEMM 64x128, XOR-swizzled LDS -------------------
__global__ __launch_bounds__(256) void gemm64_bf16_tn(
    const unsigned short* __restrict__ A,
    const unsigned short* __restrict__ Bt,
    float* __restrict__ C,
    int M, int N, int K)
{
  __shared__ __align__(16) unsigned short As[64 * 64];
  __shared__ __align__(16) unsigned short Bs[128 * 64];
  const int tid = threadIdx.x;
  const int lane = tid & 63;
  const int wid = tid >> 6;
  const int wn = wid * 32;
  const long bm = (long)blockIdx.x * 64;
  const long bn = (long)blockIdx.y * 128;

  f32x4 acc[4][2] = {};

  const int lr = tid >> 3;
  const int lc = (((tid & 7) ^ (lr & 7)) * 8);

  for (int k0 = 0; k0 < K; k0 += 64) {
#pragma unroll
    for (int i = 0; i < 2; ++i) {
      const int row = i * 32 + lr;
      const int eoff = (i * 256 + tid) * 8;
      gload_lds16(A + (bm + row) * (long)K + k0 + lc, As + eoff);
    }
#pragma unroll
    for (int i = 0; i < 4; ++i) {
      const int row = i * 32 + lr;
      const int eoff = (i * 256 + tid) * 8;
      gload_lds16(Bt + (bn + row) * (long)K + k0 + lc, Bs + eoff);
    }
    __syncthreads();
#pragma unroll
    for (int kk = 0; kk < 2; ++kk) {
      const int rsel = lane & 15;
      const int rx = rsel & 7;
      const int ko8 = kk * 4 + (lane >> 4);
      const int koz = ((ko8 ^ rx) << 3);
      bf16x8 av[4], bv[2];
#pragma unroll
      for (int m = 0; m < 4; ++m)
        av[m] = *(const bf16x8*)(As + (m * 16 + rsel) * 64 + koz);
#pragma unroll
      for (int n = 0; n < 2; ++n)
        bv[n] = *(const bf16x8*)(Bs + (wn + n * 16 + rsel) * 64 + koz);
#pragma unroll
      for (int m = 0; m < 4; ++m)
#pragma unroll
        for (int n = 0; n < 2; ++n)
          acc[m][n] = __builtin_amdgcn_mfma_f32_16x16x32_bf16(av[m], bv[n], acc[m][n], 0, 0, 0);
    }
    __syncthreads();
  }
  const int crow0 = (lane >> 4) * 4;
  const int ccol = lane & 15;
#pragma unroll
  for (int m = 0; m < 4; ++m)
#pragma unroll
    for (int n = 0; n < 2; ++n) {
      const long r = bm + m * 16 + crow0;
      const long c = bn + wn + n * 16 + ccol;
#pragma unroll
      for (int q = 0; q < 4; ++q)
        C[(r + q) * (long)N + c] = acc[m][n][q];
    }
}

// dual-operand variant: blockIdx.z picks operand set (fuses 2 independent GEMMs)
__global__ __launch_bounds__(256) void gemm64_dual(
    const unsigned short* __restrict__ A0, const unsigned short* __restrict__ B0,
    float* __restrict__ C0, int N0, int K0,
    const unsigned short* __restrict__ A1, const unsigned short* __restrict__ B1,
    float* __restrict__ C1, int N1, int K1)
{
  __shared__ __align__(16) unsigned short As[64 * 64];
  __shared__ __align__(16) unsigned short Bs[128 * 64];
  const bool z = blockIdx.z != 0;
  const unsigned short* A  = z ? A1 : A0;
  const unsigned short* Bt = z ? B1 : B0;
  float* C = z ? C1 : C0;
  const int N = z ? N1 : N0;
  const int K = z ? K1 : K0;

  const int tid = threadIdx.x;
  const int lane = tid & 63;
  const int wid = tid >> 6;
  const int wn = wid * 32;
  const long bm = (long)blockIdx.x * 64;
  const long bn = (long)blockIdx.y * 128;

  f32x4 acc[4][2] = {};

  const int lr = tid >> 3;
  const int lc = (((tid & 7) ^ (lr & 7)) * 8);

  for (int k0 = 0; k0 < K; k0 += 64) {
#pragma unroll
    for (int i = 0; i < 2; ++i) {
      const int row = i * 32 + lr;
      const int eoff = (i * 256 + tid) * 8;
      gload_lds16(A + (bm + row) * (long)K + k0 + lc, As + eoff);
    }
#pragma unroll
    for (int i = 0; i < 4; ++i) {
      const int row = i * 32 + lr;
      const int eoff = (i * 256 + tid) * 8;
      gload_lds16(Bt + (bn + row) * (long)K + k0 + lc, Bs + eoff);
    }
    __syncthreads();
#pragma unroll
    for (int kk = 0; kk < 2; ++kk) {
      const int rsel = lane & 15;
      const int rx = rsel & 7;
      const int ko8 = kk * 4 + (lane >> 4);
      const int koz = ((ko8 ^ rx) << 3);
      bf16x8 av[4], bv[2];
#pragma unroll
      for (int m = 0; m < 4; ++m)
        av[m] = *(const bf16x8*)(As + (m * 16 + rsel) * 64 + koz);
#pragma unroll
      for (int n = 0; n < 2; ++n)
        bv[n] = *(const bf16x8*)(Bs + (wn + n * 16 + rsel) * 64 + koz);
#pragma unroll
      for (int m = 0; m < 4; ++m)
#pragma unroll
        for (int n = 0; n < 2; ++n)
          acc[m][n] = __builtin_amdgcn_mfma_f32_16x16x32_bf16(av[m], bv[n], acc[m][n], 0, 0, 0);
    }
    __syncthreads();
  }
  const int crow0 = (lane >> 4) * 4;
  const int ccol = lane & 15;
#pragma unroll
  for (int m = 0; m < 4; ++m)
#pragma unroll
    for (int n = 0; n < 2; ++n) {
      const long r = bm + m * 16 + crow0;
      const long c = bn + wn + n * 16 + ccol;
#pragma unroll
      for (int q = 0; q < 4; ++q)
        C[(r + q) * (long)N + c] = acc[m][n][q];
    }
}

// ---------------- small helpers ----------------
__global__ void zero_i32(int* p, int n) { int i = blockIdx.x*256+threadIdx.x; if (i < n) p[i] = 0; }
__global__ void zero_f32(float* p, int n) { int i = blockIdx.x*256+threadIdx.x; if (i < n) p[i] = 0.f; }
__global__ void fill_ones(float* p, int n) { int i = blockIdx.x*256+threadIdx.x; if (i < n) p[i] = 1.f; }

__global__ void deg_edges(const int* __restrict__ ei, const float* __restrict__ ew,
                          float* __restrict__ deg, int E) {
  int e = blockIdx.x*256+threadIdx.x;
  if (e < E) atomicAdd(&deg[ei[E + e]], ew[e]);
}
__global__ void make_dinv(float* p, int n) {
  int i = blockIdx.x*256+threadIdx.x; if (i < n) p[i] = rsqrtf(p[i]);
}
__global__ void flag_set(const int* __restrict__ idxa, int B_, int* __restrict__ flag) {
  int i = blockIdx.x*256+threadIdx.x; if (i < B_) flag[idxa[i]] = 1;
}
__global__ void flag_slot(int* __restrict__ flag, int n, int* __restrict__ ctr,
                          int* __restrict__ slotnode) {
  int i = blockIdx.x*256+threadIdx.x;
  if (i < n && flag[i]) {
    int s = atomicAdd(ctr, 1);
    flag[i] = s + 1;
    slotnode[s] = i;
  }
}
__global__ void hist_edges(const int* __restrict__ ei, const int* __restrict__ flag,
                           int* __restrict__ cnt, int E) {
  int e = blockIdx.x*256+threadIdx.x; if (e >= E) return;
  int s = flag[ei[E + e]];
  if (s) atomicAdd(&cnt[s - 1], 1);
}
__global__ void scan2048(const int* __restrict__ cnt, int* __restrict__ rowptr) {
  __shared__ int part[256];
  int tid = threadIdx.x;
  int base = tid * 8;
  int vals[8]; int s = 0;
#pragma unroll
  for (int i = 0; i < 8; ++i) { vals[i] = s; s += cnt[base + i]; }
  part[tid] = s;
  __syncthreads();
  if (tid == 0) { int r = 0; for (int i = 0; i < 256; ++i) { int t = part[i]; part[i] = r; r += t; } }
  __syncthreads();
  int off = part[tid];
#pragma unroll
  for (int i = 0; i < 8; ++i) rowptr[base + i] = off + vals[i];
  if (tid == 255) rowptr[2048] = off + s;
}
__global__ void fill_edges(const int* __restrict__ ei, const float* __restrict__ ew,
                           const float* __restrict__ dinv, const int* __restrict__ flag,
                           const int* __restrict__ rowptr, int* __restrict__ fillp,
                           int* __restrict__ esrc, float* __restrict__ ecoef, int E) {
  int e = blockIdx.x*256+threadIdx.x; if (e >= E) return;
  int dst = ei[E + e];
  int s = flag[dst]; if (!s) return;
  int src = ei[e];
  int pos = rowptr[s - 1] + atomicAdd(&fillp[s - 1], 1);
  esrc[pos] = src;
  ecoef[pos] = ew[e] * dinv[src] * dinv[dst];
}

// fused dual-graph gather: blocks [0,2048) = d-graph, [2048,4096) = p-graph.
__global__ __launch_bounds__(256) void gather_agg2(
    const float* __restrict__ Xd, const float* __restrict__ dinv_d,
    const int* __restrict__ slot_d, const int* __restrict__ rp_d,
    const int* __restrict__ es_d, const float* __restrict__ ec_d,
    const int* __restrict__ nflag_d, unsigned short* __restrict__ aggd, int Kd,
    const float* __restrict__ Xp, const float* __restrict__ dinv_p,
    const int* __restrict__ slot_p, const int* __restrict__ rp_p,
    const int* __restrict__ es_p, const float* __restrict__ ec_p,
    const int* __restrict__ nflag_p, unsigned short* __restrict__ aggp, int Kp)
{
  __shared__ int   s_src[512];
  __shared__ float s_coef[512];
  const int tid = threadIdx.x;
  const bool isP = blockIdx.x >= 2048;
  const int s = isP ? (int)blockIdx.x - 2048 : (int)blockIdx.x;
  const float* X      = isP ? Xp : Xd;
  const float* dinv   = isP ? dinv_p : dinv_d;
  const int*   slot   = isP ? slot_p : slot_d;
  const int*   rp     = isP ? rp_p : rp_d;
  const int*   es     = isP ? es_p : es_d;
  const float* ec     = isP ? ec_p : ec_d;
  const int    nflag  = isP ? *nflag_p : *nflag_d;
  unsigned short* agg = isP ? aggp : aggd;
  const int    K      = isP ? Kp : Kd;
  if (s >= nflag) return;

  const int n = slot[s];
  const float dn = dinv[n];
  const float selfc = dn * dn;
  const int e0 = rp[s], e1 = rp[s + 1];
  const int K4 = K >> 2;
  const float4* xn = (const float4*)(X + (long)n * K);

  float4 acc[3];
  int ncols = 0;
#pragma unroll
  for (int j = 0; j < 3; ++j) {
    int c = tid + j * 256;
    if (c < K4) {
      float4 v = xn[c];
      acc[j] = make_float4(selfc * v.x, selfc * v.y, selfc * v.z, selfc * v.w);
      ncols = j + 1;
    }
  }

  for (int base = e0; base < e1; base += 512) {
    int cnt = min(512, e1 - base);
    __syncthreads();
    for (int i = tid; i < cnt; i += 256) { s_src[i] = es[base + i]; s_coef[i] = ec[base + i]; }
    __syncthreads();
#pragma unroll 4
    for (int e = 0; e < cnt; ++e) {
      const float4* xr = (const float4*)(X + (long)s_src[e] * K);
      const float cf = s_coef[e];
#pragma unroll
      for (int j = 0; j < 3; ++j) {
        int c = tid + j * 256;
        if (j < ncols) {
          float4 v = xr[c];
          acc[j].x += cf * v.x; acc[j].y += cf * v.y;
          acc[j].z += cf * v.z; acc[j].w += cf * v.w;
        }
      }
    }
  }

  unsigned short* ar = agg + (long)s * K;
#pragma unroll
  for (int j = 0; j < 3; ++j) {
    int c = tid + j * 256;
    if (j < ncols) {
      ushort4 o;
      o.x = f2b(acc[j].x); o.y = f2b(acc[j].y);
      o.z = f2b(acc[j].z); o.w = f2b(acc[j].w);
      *(ushort4*)(ar + 4 * c) = o;
    }
  }
}

__global__ void gatherA(const unsigned short* __restrict__ aggb, const int* __restrict__ idxa,
                        const int* __restrict__ flag, unsigned short* __restrict__ Ab,
                        int K, int Kp) {
  int idx = blockIdx.x*256+threadIdx.x;
  if (idx >= 2048 * Kp) return;
  int b = idx / Kp, k = idx % Kp;
  Ab[idx] = (k < K) ? aggb[(long)(flag[idxa[b]] - 1) * K + k] : (unsigned short)0;
}

// Wt[Np][Kp] = bf16(W[K,N]^T), zero-padded
__global__ void transposeW(const float* __restrict__ W, unsigned short* __restrict__ Wt,
                           int K, int N, int Kp, int Np_) {
  __shared__ float tile[32][33];
  int k0 = blockIdx.x * 32, n0 = blockIdx.y * 32;
  for (int i = threadIdx.y; i < 32; i += 8) {
    int k = k0 + i, n = n0 + threadIdx.x;
    tile[i][threadIdx.x] = (k < K && n < N) ? W[(size_t)k * N + n] : 0.f;
  }
  __syncthreads();
  for (int i = threadIdx.y; i < 32; i += 8) {
    int n = n0 + i, k = k0 + threadIdx.x;
    if (n < Np_ && k < Kp) Wt[(size_t)n * Kp + k] = f2b(tile[threadIdx.x][i]);
  }
}

__global__ void colstats(const float* __restrict__ Z, int ldz, int cols,
                         float* __restrict__ csum, float* __restrict__ csumsq) {
  int col = blockIdx.x * 256 + threadIdx.x;
  if (col >= cols) return;
  int r0 = blockIdx.y * 128;
  float s = 0.f, s2 = 0.f;
  for (int r = r0; r < r0 + 128; ++r) {
    float v = Z[(long)r * ldz + col];
    s += v; s2 += v * v;
  }
  atomicAdd(&csum[col], s);
  atomicAdd(&csumsq[col], s2);
}

__global__ void bn_finalize(const float* __restrict__ csum, const float* __restrict__ csumsq,
                            const float* __restrict__ g, const float* __restrict__ beta,
                            float* __restrict__ scale, float* __restrict__ shift, int cols) {
  int j = blockIdx.x*256+threadIdx.x; if (j >= cols) return;
  const float invB = 1.f / 2048.f;
  float m = csum[j] * invB;
  float v = fmaxf(csumsq[j] * invB - m * m, 0.f);
  float sc = g[j] * rsqrtf(v + 1e-5f);
  scale[j] = sc;
  shift[j] = beta[j] - m * sc;
}

__global__ void apply_act(const float* __restrict__ Z, int ldz, int total, int cols,
                          const float* __restrict__ scale, const float* __restrict__ shift,
                          int leaky,
                          float* __restrict__ f32out, int ldf,
                          unsigned short* __restrict__ b16out, int ldb) {
  int idx = blockIdx.x*256+threadIdx.x;
  if (idx >= total) return;
  int b = idx / cols, j = idx % cols;
  float v = Z[(long)b * ldz + j];
  v = scale ? v * scale[j] + shift[j] : v + shift[j];
  v = (v >= 0.f) ? v : (leaky ? 0.01f * v : 0.f);
  if (f32out) f32out[(long)b * ldf + j] = v;
  if (b16out) b16out[(long)b * ldb + j] = f2b(v);
}

__global__ void feat_copy(const float* __restrict__ dv, const float* __restrict__ pe,
                          float* __restrict__ f32out, unsigned short* __restrict__ b16out) {
  int idx = blockIdx.x*256+threadIdx.x;
  if (idx >= 2048 * 1324) return;
  int b = idx / 1324, c = idx % 1324;
  float v = (c < 300) ? dv[b * 300 + c] : pe[(long)b * 1024 + (c - 300)];
  f32out[(long)b * 3372 + c] = v;
  b16out[(long)b * 3456 + c] = f2b(v);
}
__global__ void feat_pad(unsigned short* __restrict__ b16out) {
  int idx = blockIdx.x*256+threadIdx.x;
  if (idx >= 2048 * 84) return;
  int b = idx / 84, c = 3372 + idx % 84;
  b16out[(long)b * 3456 + c] = 0;
}

__global__ void yfinal(const float* __restrict__ h5, const float* __restrict__ W2,
                       const float* __restrict__ b2, float* __restrict__ y) {
  int b = blockIdx.x*256+threadIdx.x;
  if (b >= 2048) return;
  float s = b2[0];
  for (int k = 0; k < 64; ++k) s += h5[b * 64 + k] * W2[k];
  y[b] = s;
}

extern "C" void kernel_launch(void* const* d_in, const int* in_sizes, int n_in,
                              void* d_out, int out_size, void* d_ws, size_t ws_size,
                              hipStream_t stream) {
  (void)in_sizes; (void)n_in; (void)out_size; (void)ws_size;
  const int*   d_index = (const int*)d_in[0];
  const int*   p_index = (const int*)d_in[1];
  const float* d_vecs  = (const float*)d_in[2];
  const float* p_emb   = (const float*)d_in[3];
  const float* d_ecfps = (const float*)d_in[4];
  const int*   d_ei    = (const int*)d_in[5];
  const float* d_ew    = (const float*)d_in[6];
  const float* p_gos   = (const float*)d_in[7];
  const int*   p_ei    = (const int*)d_in[8];
  const float* p_ew    = (const float*)d_in[9];
  const float* d_gcn_W = (const float*)d_in[10];
  const float* d_gcn_b = (const float*)d_in[11];
  const float* p_gcn_W = (const float*)d_in[12];
  const float* p_gcn_b = (const float*)d_in[13];
  const float* enc_W1  = (const float*)d_in[14];
  const float* enc_g1  = (const float*)d_in[16];
  const float* enc_be1 = (const float*)d_in[17];
  const float* enc_W2  = (const float*)d_in[18];
  const float* enc_g2  = (const float*)d_in[20];
  const float* enc_be2 = (const float*)d_in[21];
  const float* dec_W1  = (const float*)d_in[22];
  const float* dec_g1  = (const float*)d_in[24];
  const float* dec_be1 = (const float*)d_in[25];
  const float* dec_W2  = (const float*)d_in[26];
  const float* dec_g2  = (const float*)d_in[28];
  const float* dec_be2 = (const float*)d_in[29];
  const float* out_W1  = (const float*)d_in[30];
  const float* out_g1  = (const float*)d_in[32];
  const float* out_be1 = (const float*)d_in[33];
  const float* out_W2  = (const float*)d_in[34];
  const float* out_b2  = (const float*)d_in[35];

  float* out = (float*)d_out;
  float* y_out    = out;
  float* enc_out  = out + 2048;
  float* dec_out  = out + 526336;
  float* feat_out = out + 7432192;

  char* ws = (char*)d_ws;
  size_t off = 0;
  auto alloc = [&](size_t bytes) {
    size_t o = off; off = (off + bytes + 255) & ~(size_t)255; return (void*)(ws + o);
  };
  int* iz = (int*)alloc((size_t)23194 * 4);
  int* flag_d = iz;              // 10000
  int* flag_p = iz + 10000;      // 5000
  int* cnt_d  = iz + 15000;      // 2048
  int* cnt_p  = iz + 17048;      // 2048
  int* fill_d = iz + 19096;      // 2048
  int* fill_p = iz + 21144;      // 2048
  int* ctr    = iz + 23192;      // 2
  int* slotnode_d = (int*)alloc(2048 * 4);
  int* slotnode_p = (int*)alloc(2048 * 4);
  int* rowptr_d = (int*)alloc(2049 * 4);
  int* rowptr_p = (int*)alloc(2049 * 4);
  int* esrc_d  = (int*)alloc((size_t)65536 * 4);
  float* ecoef_d = (float*)alloc((size_t)65536 * 4);
  int* esrc_p  = (int*)alloc((size_t)25000 * 4);
  float* ecoef_p = (float*)alloc((size_t)25000 * 4);
  float* deg   = (float*)alloc((size_t)15000 * 4);
  float* deg_d = deg;
  float* deg_p = deg + 10000;
  unsigned short* aggd_b = (unsigned short*)alloc((size_t)2048 * 1024 * 2);
  unsigned short* aggp_b = (unsigned short*)alloc((size_t)2048 * 2812 * 2);
  unsigned short* Adb   = (unsigned short*)alloc((size_t)2048 * 1024 * 2);
  unsigned short* Apb   = (unsigned short*)alloc((size_t)2048 * 2816 * 2);
  unsigned short* WdT   = (unsigned short*)alloc((size_t)1024 * 1024 * 2);
  unsigned short* WpT   = (unsigned short*)alloc((size_t)1024 * 2816 * 2);
  unsigned short* eW1T  = (unsigned short*)alloc((size_t)1024 * 3456 * 2);
  unsigned short* eW2T  = (unsigned short*)alloc((size_t)256 * 1024 * 2);
  unsigned short* dhT   = (unsigned short*)alloc((size_t)1152 * 256 * 2);  // dec_W1^T ++ out_W1^T
  unsigned short* dW2T  = (unsigned short*)alloc((size_t)3456 * 1024 * 2);
  unsigned short* featb = (unsigned short*)alloc((size_t)2048 * 3456 * 2);
  float* Z    = (float*)alloc((size_t)2048 * 3456 * 4);
  float* Zp   = Z + (size_t)2048 * 1024;       // second half for fused dual GEMM
  unsigned short* h1b  = (unsigned short*)alloc((size_t)2048 * 1024 * 2);
  unsigned short* encb = (unsigned short*)alloc((size_t)2048 * 256 * 2);
  unsigned short* h3b  = (unsigned short*)alloc((size_t)2048 * 1024 * 2);
  float* h5   = (float*)alloc((size_t)2048 * 64 * 4);
  float* csum = (float*)alloc((size_t)2 * 3456 * 4);
  float* csumsq = csum + 3456;
  float* bscale = (float*)alloc((size_t)2 * 3456 * 4);
  float* bshift = bscale + 3456;

  // ---- GCN prep ----
  zero_i32<<<CDIV(23194,256),256,0,stream>>>(iz, 23194);
  fill_ones<<<CDIV(15000,256),256,0,stream>>>(deg, 15000);
  deg_edges<<<CDIV(65536,256),256,0,stream>>>(d_ei, d_ew, deg_d, 65536);
  deg_edges<<<CDIV(25000,256),256,0,stream>>>(p_ei, p_ew, deg_p, 25000);
  make_dinv<<<CDIV(15000,256),256,0,stream>>>(deg, 15000);
  flag_set<<<8,256,0,stream>>>(d_index, 2048, flag_d);
  flag_set<<<8,256,0,stream>>>(p_index, 2048, flag_p);
  flag_slot<<<CDIV(10000,256),256,0,stream>>>(flag_d, 10000, ctr, slotnode_d);
  flag_slot<<<CDIV(5000,256),256,0,stream>>>(flag_p, 5000, ctr + 1, slotnode_p);
  hist_edges<<<CDIV(65536,256),256,0,stream>>>(d_ei, flag_d, cnt_d, 65536);
  hist_edges<<<CDIV(25000,256),256,0,stream>>>(p_ei, flag_p, cnt_p, 25000);
  scan2048<<<1,256,0,stream>>>(cnt_d, rowptr_d);
  scan2048<<<1,256,0,stream>>>(cnt_p, rowptr_p);
  fill_edges<<<CDIV(65536,256),256,0,stream>>>(d_ei, d_ew, deg_d, flag_d, rowptr_d, fill_d,
                                               esrc_d, ecoef_d, 65536);
  fill_edges<<<CDIV(25000,256),256,0,stream>>>(p_ei, p_ew, deg_p, flag_p, rowptr_p, fill_p,
                                               esrc_p, ecoef_p, 25000);
  gather_agg2<<<4096,256,0,stream>>>(
      d_ecfps, deg_d, slotnode_d, rowptr_d, esrc_d, ecoef_d, ctr, aggd_b, 1024,
      p_gos,   deg_p, slotnode_p, rowptr_p, esrc_p, ecoef_p, ctr + 1, aggp_b, 2812);
  gatherA<<<CDIV(2048*1024,256),256,0,stream>>>(aggd_b, d_index, flag_d, Adb, 1024, 1024);
  gatherA<<<CDIV(2048*2816,256),256,0,stream>>>(aggp_b, p_index, flag_p, Apb, 2812, 2816);

  // ---- weight transposes to bf16 [N,K] (padded) ----
  dim3 tb(32, 8);
  transposeW<<<dim3(32, 32), tb, 0, stream>>>(d_gcn_W, WdT, 1024, 1024, 1024, 1024);
  transposeW<<<dim3(88, 32), tb, 0, stream>>>(p_gcn_W, WpT, 2812, 1024, 2816, 1024);
  transposeW<<<dim3(108, 32), tb, 0, stream>>>(enc_W1, eW1T, 3372, 1024, 3456, 1024);
  transposeW<<<dim3(32, 8),  tb, 0, stream>>>(enc_W2, eW2T, 1024, 256, 1024, 256);
  transposeW<<<dim3(8, 32),  tb, 0, stream>>>(dec_W1, dhT, 256, 1024, 256, 1024);
  transposeW<<<dim3(8, 4),   tb, 0, stream>>>(out_W1, dhT + (size_t)1024 * 256, 256, 64, 256, 128);
  transposeW<<<dim3(32, 108),tb, 0, stream>>>(dec_W2, dW2T, 1024, 3372, 1024, 3456);

  // ---- GCN GEMMs (fused dual launch) -> feature ----
  gemm64_dual<<<dim3(32,8,2),256,0,stream>>>(Adb, WdT, Z, 1024, 1024,
                                             Apb, WpT, Zp, 1024, 2816);
  apply_act<<<CDIV(2048*1024,256),256,0,stream>>>(Z, 1024, 2048*1024, 1024,
      nullptr, d_gcn_b, 1, feat_out + 1324, 3372, featb + 1324, 3456);
  apply_act<<<CDIV(2048*1024,256),256,0,stream>>>(Zp, 1024, 2048*1024, 1024,
      nullptr, p_gcn_b, 1, feat_out + 2348, 3372, featb + 2348, 3456);
  feat_copy<<<CDIV(2048*1324,256),256,0,stream>>>(d_vecs, p_emb, feat_out, featb);
  feat_pad<<<CDIV(2048*84,256),256,0,stream>>>(featb);

  // ---- encoder L1 ----
  gemm64_bf16_tn<<<dim3(32,8),256,0,stream>>>(featb, eW1T, Z, 2048, 1024, 3456);
  zero_f32<<<CDIV(2*3456,256),256,0,stream>>>(csum, 2*3456);
  colstats<<<dim3(4,16),256,0,stream>>>(Z, 1024, 1024, csum, csumsq);
  bn_finalize<<<4,256,0,stream>>>(csum, csumsq, enc_g1, enc_be1, bscale, bshift, 1024);
  apply_act<<<CDIV(2048*1024,256),256,0,stream>>>(Z, 1024, 2048*1024, 1024,
      bscale, bshift, 0, nullptr, 0, h1b, 1024);

  // ---- encoder L2 -> encoded ----
  gemm64_bf16_tn<<<dim3(32,2),256,0,stream>>>(h1b, eW2T, Z, 2048, 256, 1024);
  zero_f32<<<CDIV(2*3456,256),256,0,stream>>>(csum, 2*3456);
  colstats<<<dim3(1,16),256,0,stream>>>(Z, 256, 256, csum, csumsq);
  bn_finalize<<<1,256,0,stream>>>(csum, csumsq, enc_g2, enc_be2, bscale, bshift, 256);
  apply_act<<<CDIV(2048*256,256),256,0,stream>>>(Z, 256, 2048*256, 256,
      bscale, bshift, 0, enc_out, 256, encb, 256);

  // ---- decoder L1 + head GEMM fused: [2048,256] x [256,1152] ----
  gemm64_bf16_tn<<<dim3(32,9),256,0,stream>>>(encb, dhT, Z, 2048, 1152, 256);
  // dec L1 part (cols 0..1023)
  zero_f32<<<CDIV(2*3456,256),256,0,stream>>>(csum, 2*3456);
  colstats<<<dim3(4,16),256,0,stream>>>(Z, 1152, 1024, csum, csumsq);
  bn_finalize<<<4,256,0,stream>>>(csum, csumsq, dec_g1, dec_be1, bscale, bshift, 1024);
  apply_act<<<CDIV(2048*1024,256),256,0,stream>>>(Z, 1152, 2048*1024, 1024,
      bscale, bshift, 0, nullptr, 0, h3b, 1024);
  // head part (cols 1024..1087)
  colstats<<<dim3(1,16),256,0,stream>>>(Z + 1024, 1152, 64, csum + 3200, csumsq + 3200 - 3456 + 3456);
  bn_finalize<<<1,256,0,stream>>>(csum + 3200, csumsq + 3200, out_g1, out_be1,
                                  bscale + 3200, bshift + 3200, 64);
  apply_act<<<CDIV(2048*64,256),256,0,stream>>>(Z + 1024, 1152, 2048*64, 64,
      bscale + 3200, bshift + 3200, 1, h5, 64, nullptr, 0);
  yfinal<<<8,256,0,stream>>>(h5, out_W2, out_b2, y_out);

  // ---- decoder L2 -> decoded ----
  gemm_bf16_tn<<<dim3(16,27),256,0,stream>>>(h3b, dW2T, Z, 2048, 3456, 1024);
  zero_f32<<<CDIV(2*3456,256),256,0,stream>>>(csum, 2*3456);
  colstats<<<dim3(14,16),256,0,stream>>>(Z, 3456, 3372, csum, csumsq);
  bn_finalize<<<14,256,0,stream>>>(csum, csumsq, dec_g2, dec_be2, bscale, bshift, 3372);
  apply_act<<<CDIV(2048*3372,256),256,0,stream>>>(Z, 3456, 2048*3372, 3372,
      bscale, bshift, 0, dec_out, 3372, nullptr, 0);
}